// Round 7
// baseline (518.120 us; speedup 1.0000x reference)
//
#include <hip/hip_runtime.h>

#define NN 1024
#define KK 128

typedef __attribute__((ext_vector_type(8))) short bf16x8;
typedef __attribute__((ext_vector_type(4))) float f32x4;
typedef __attribute__((ext_vector_type(8))) unsigned short u16x8;

__device__ __forceinline__ unsigned int bf16rne(float x) {
    unsigned int u = __float_as_uint(x);
    return (u + 0x7FFFu + ((u >> 16) & 1u)) >> 16;
}

__device__ __forceinline__ void split8(const float* xs, bf16x8& h8, bf16x8& l8) {
    #pragma unroll
    for (int j = 0; j < 8; ++j) {
        unsigned int hb = bf16rne(xs[j]);
        float hf = __uint_as_float(hb << 16);
        h8[j] = (short)hb;
        l8[j] = (short)bf16rne(xs[j] - hf);
    }
}

// ---------------------------------------------------------------------------
// MFMA sandwich: Out_n = B_n^T (A_n B_n)  [+ epilogue for FINAL], split-bf16.
// (unchanged from round 6 — see comments there)
// ---------------------------------------------------------------------------
template<bool FINAL>
__global__ __launch_bounds__(256) void sandwich_mfma(
    const float* __restrict__ A_, const float* __restrict__ B_,
    float* __restrict__ Out,
    const float* __restrict__ Lp, const float* __restrict__ Lq,
    const float* __restrict__ obs, const float* __restrict__ beta)
{
    __shared__ short lds_buf[69632];
    short* Bth = lds_buf;
    short* Btl = lds_buf + 17408;
    short* Tth = lds_buf + 34816;
    short* Ttl = lds_buf + 52224;
    float* pan = (float*)(lds_buf + 34816);
    __shared__ float wred[4];
    __shared__ float cs_sh;

    const int n    = blockIdx.x;
    const int tid  = threadIdx.x;
    const int lane = tid & 63;
    const int wid  = tid >> 6;
    const int wr   = wid >> 1, wc = wid & 1;
    const int lm   = lane & 15;
    const int lk   = lane >> 4;
    const size_t base = (size_t)n * (KK * KK);

    if (FINAL) {
        float s = 0.f;
        for (int j = tid; j < NN; j += 256)
            if (j != n) s += beta[(size_t)j * NN + n];
        #pragma unroll
        for (int off = 32; off >= 1; off >>= 1) s += __shfl_down(s, off);
        if ((tid & 63) == 0) wred[tid >> 6] = s;
        __syncthreads();
        if (tid == 0) cs_sh = wred[0] + wred[1] + wred[2] + wred[3];
    }

    // ---- stage Bt = B^T (hi/lo bf16) via two 64-col f32 panels ----
    #pragma unroll
    for (int cp = 0; cp < 2; ++cp) {
        #pragma unroll
        for (int it = 0; it < 8; ++it) {
            int gid = it * 256 + tid;
            int k   = gid >> 4;
            int c4  = (gid & 15) * 4;
            *(float4*)&pan[k * 66 + c4] =
                *(const float4*)(B_ + base + (size_t)k * KK + cp * 64 + c4);
        }
        __syncthreads();
        #pragma unroll
        for (int it = 0; it < 4; ++it) {
            int t  = it * 256 + tid;
            int c  = t >> 4;
            int ko = (t & 15) * 8;
            float xs[8];
            #pragma unroll
            for (int j = 0; j < 8; ++j) xs[j] = pan[(ko + j) * 66 + c];
            bf16x8 h8, l8;
            split8(xs, h8, l8);
            const int gc = cp * 64 + c;
            *(bf16x8*)&Bth[gc * 136 + ko] = h8;
            *(bf16x8*)&Btl[gc * 136 + ko] = l8;
        }
        __syncthreads();
    }

    // ================= stage 1: T = A @ B =================
    f32x4 acc[4][4];
    #pragma unroll
    for (int a = 0; a < 4; ++a)
        #pragma unroll
        for (int b = 0; b < 4; ++b) acc[a][b] = (f32x4){0.f, 0.f, 0.f, 0.f};

    #pragma unroll 1
    for (int ks = 0; ks < 4; ++ks) {
        const int k0 = ks * 32;
        bf16x8 afh[4], afl[4], bfh[4], bfl[4];
        #pragma unroll
        for (int rt = 0; rt < 4; ++rt) {
            const int r = wr * 64 + rt * 16 + lm;
            const float* ap = A_ + base + (size_t)r * KK + k0 + lk * 8;
            float4 x0 = *(const float4*)ap;
            float4 x1 = *(const float4*)(ap + 4);
            float xs[8] = {x0.x, x0.y, x0.z, x0.w, x1.x, x1.y, x1.z, x1.w};
            split8(xs, afh[rt], afl[rt]);
        }
        #pragma unroll
        for (int ct = 0; ct < 4; ++ct) {
            const int c = wc * 64 + ct * 16 + lm;
            bfh[ct] = *(const bf16x8*)&Bth[c * 136 + k0 + lk * 8];
            bfl[ct] = *(const bf16x8*)&Btl[c * 136 + k0 + lk * 8];
        }
        #pragma unroll
        for (int rt = 0; rt < 4; ++rt)
            #pragma unroll
            for (int ct = 0; ct < 4; ++ct) {
                acc[rt][ct] = __builtin_amdgcn_mfma_f32_16x16x32_bf16(
                    afh[rt], bfh[ct], acc[rt][ct], 0, 0, 0);
                acc[rt][ct] = __builtin_amdgcn_mfma_f32_16x16x32_bf16(
                    afh[rt], bfl[ct], acc[rt][ct], 0, 0, 0);
                acc[rt][ct] = __builtin_amdgcn_mfma_f32_16x16x32_bf16(
                    afl[rt], bfh[ct], acc[rt][ct], 0, 0, 0);
            }
    }

    // ---- T -> Tt[c][k] hi/lo ----
    #pragma unroll
    for (int rt = 0; rt < 4; ++rt)
        #pragma unroll
        for (int ct = 0; ct < 4; ++ct) {
            const int col  = wc * 64 + ct * 16 + lm;
            const int row0 = wr * 64 + rt * 16 + lk * 4;
            unsigned short h[4], l[4];
            #pragma unroll
            for (int j = 0; j < 4; ++j) {
                float x = acc[rt][ct][j];
                unsigned int hb = bf16rne(x);
                h[j] = (unsigned short)hb;
                l[j] = (unsigned short)bf16rne(x - __uint_as_float(hb << 16));
            }
            *(ushort4*)&Tth[col * 136 + row0] = make_ushort4(h[0], h[1], h[2], h[3]);
            *(ushort4*)&Ttl[col * 136 + row0] = make_ushort4(l[0], l[1], l[2], l[3]);
        }
    __syncthreads();

    // ================= stage 2: Out = B^T @ T =================
    f32x4 acc2[4][4];
    #pragma unroll
    for (int a = 0; a < 4; ++a)
        #pragma unroll
        for (int b = 0; b < 4; ++b) acc2[a][b] = (f32x4){0.f, 0.f, 0.f, 0.f};

    #pragma unroll 1
    for (int ks = 0; ks < 4; ++ks) {
        const int k0 = ks * 32;
        bf16x8 afh[4], afl[4], bfh[4], bfl[4];
        #pragma unroll
        for (int rt = 0; rt < 4; ++rt) {
            const int r = wr * 64 + rt * 16 + lm;
            afh[rt] = *(const bf16x8*)&Bth[r * 136 + k0 + lk * 8];
            afl[rt] = *(const bf16x8*)&Btl[r * 136 + k0 + lk * 8];
        }
        #pragma unroll
        for (int ct = 0; ct < 4; ++ct) {
            const int c = wc * 64 + ct * 16 + lm;
            bfh[ct] = *(const bf16x8*)&Tth[c * 136 + k0 + lk * 8];
            bfl[ct] = *(const bf16x8*)&Ttl[c * 136 + k0 + lk * 8];
        }
        #pragma unroll
        for (int rt = 0; rt < 4; ++rt)
            #pragma unroll
            for (int ct = 0; ct < 4; ++ct) {
                acc2[rt][ct] = __builtin_amdgcn_mfma_f32_16x16x32_bf16(
                    afh[rt], bfh[ct], acc2[rt][ct], 0, 0, 0);
                acc2[rt][ct] = __builtin_amdgcn_mfma_f32_16x16x32_bf16(
                    afh[rt], bfl[ct], acc2[rt][ct], 0, 0, 0);
                acc2[rt][ct] = __builtin_amdgcn_mfma_f32_16x16x32_bf16(
                    afl[rt], bfh[ct], acc2[rt][ct], 0, 0, 0);
            }
    }

    // ================= epilogue + store =================
    const float csv = FINAL ? cs_sh : 0.f;
    #pragma unroll
    for (int rt = 0; rt < 4; ++rt)
        #pragma unroll
        for (int ct = 0; ct < 4; ++ct) {
            const int col  = wc * 64 + ct * 16 + lm;
            const int row0 = wr * 64 + rt * 16 + lk * 4;
            #pragma unroll
            for (int j = 0; j < 4; ++j) {
                const int row = row0 + j;
                float o = acc2[rt][ct][j];
                if (FINAL) {
                    o += Lp[base + (size_t)row * KK + col]
                       + csv * Lq[base + (size_t)row * KK + col]
                       + obs[(size_t)row * KK + col];
                }
                Out[base + (size_t)row * KK + col] = o;
            }
        }
}

// ---------------------------------------------------------------------------
// Split-transpose: S (f32, [1024][16384]) -> Sth/Stl (bf16, [16384][1024]).
// ---------------------------------------------------------------------------
__global__ __launch_bounds__(256) void split_transpose_kernel(
    const float* __restrict__ S,
    unsigned short* __restrict__ Th, unsigned short* __restrict__ Tl)
{
    __shared__ float tile[128][132];
    const int tid = threadIdx.x;
    const int c0  = blockIdx.x * 128;
    const int k0  = blockIdx.y * 128;

    #pragma unroll
    for (int it = 0; it < 16; ++it) {
        int gid = it * 256 + tid;
        int kk  = gid >> 5;
        int c4  = (gid & 31) * 4;
        float4 v = *(const float4*)(S + (size_t)(k0 + kk) * 16384 + c0 + c4);
        *(float4*)&tile[kk][c4] = v;
    }
    __syncthreads();
    #pragma unroll
    for (int it = 0; it < 8; ++it) {
        int gid = it * 256 + tid;
        int c   = gid >> 4;
        int kc  = (gid & 15) * 8;
        u16x8 h, l;
        #pragma unroll
        for (int j = 0; j < 8; ++j) {
            float x = tile[kc + j][c];
            unsigned int hb = bf16rne(x);
            float hf = __uint_as_float(hb << 16);
            h[j] = (unsigned short)hb;
            l[j] = (unsigned short)bf16rne(x - hf);
        }
        size_t o = (size_t)(c0 + c) * 1024 + k0 + kc;
        *(u16x8*)(Th + o) = h;
        *(u16x8*)(Tl + o) = l;
    }
}

// ---------------------------------------------------------------------------
// Big GEMM via MFMA, split-bf16 (unchanged from round 5/6).
// ---------------------------------------------------------------------------
__global__ __launch_bounds__(256) void gemm_beta_mfma(
    const float* __restrict__ beta,
    const unsigned short* __restrict__ Sth,
    const unsigned short* __restrict__ Stl,
    float* __restrict__ W)
{
    __shared__ unsigned short Ah[128][40], Al[128][40];
    __shared__ unsigned short Bh[128][40], Bl[128][40];

    const int tid  = threadIdx.x;
    const int lane = tid & 63;
    const int wid  = tid >> 6;
    const int wr   = wid >> 1, wc = wid & 1;
    const int lm   = lane & 15;
    const int lk   = lane >> 4;
    const int i0   = blockIdx.y * 128;
    const int cb   = blockIdx.x * 128;

    f32x4 acc[4][4];
    #pragma unroll
    for (int a = 0; a < 4; ++a)
        #pragma unroll
        for (int b = 0; b < 4; ++b) acc[a][b] = (f32x4){0.f, 0.f, 0.f, 0.f};

    for (int k0 = 0; k0 < 1024; k0 += 32) {
        #pragma unroll
        for (int it = 0; it < 4; ++it) {
            int gid = it * 256 + tid;
            int r   = gid >> 3;
            int c4  = (gid & 7) * 4;
            int gi  = i0 + r;
            float4 v = *(const float4*)(beta + (size_t)gi * NN + k0 + c4);
            if (gi == k0 + c4 + 0) v.x = 0.f;
            if (gi == k0 + c4 + 1) v.y = 0.f;
            if (gi == k0 + c4 + 2) v.z = 0.f;
            if (gi == k0 + c4 + 3) v.w = 0.f;
            float xs[4] = {v.x, v.y, v.z, v.w};
            unsigned short hs[4], ls[4];
            #pragma unroll
            for (int j = 0; j < 4; ++j) {
                unsigned int hb = bf16rne(xs[j]);
                hs[j] = (unsigned short)hb;
                ls[j] = (unsigned short)bf16rne(xs[j] - __uint_as_float(hb << 16));
            }
            *(ushort4*)&Ah[r][c4] = make_ushort4(hs[0], hs[1], hs[2], hs[3]);
            *(ushort4*)&Al[r][c4] = make_ushort4(ls[0], ls[1], ls[2], ls[3]);
        }
        #pragma unroll
        for (int it = 0; it < 2; ++it) {
            int gid = it * 256 + tid;
            int c   = gid >> 2;
            int kc  = (gid & 3) * 8;
            size_t o = (size_t)(cb + c) * 1024 + k0 + kc;
            *(u16x8*)&Bh[c][kc] = *(const u16x8*)(Sth + o);
            *(u16x8*)&Bl[c][kc] = *(const u16x8*)(Stl + o);
        }
        __syncthreads();

        bf16x8 afh[4], afl[4], bfh[4], bfl[4];
        #pragma unroll
        for (int rt = 0; rt < 4; ++rt) {
            const int r = wr * 64 + rt * 16 + lm;
            afh[rt] = *(const bf16x8*)&Ah[r][lk * 8];
            afl[rt] = *(const bf16x8*)&Al[r][lk * 8];
        }
        #pragma unroll
        for (int ct = 0; ct < 4; ++ct) {
            const int c = wc * 64 + ct * 16 + lm;
            bfh[ct] = *(const bf16x8*)&Bh[c][lk * 8];
            bfl[ct] = *(const bf16x8*)&Bl[c][lk * 8];
        }
        #pragma unroll
        for (int rt = 0; rt < 4; ++rt)
            #pragma unroll
            for (int ct = 0; ct < 4; ++ct) {
                acc[rt][ct] = __builtin_amdgcn_mfma_f32_16x16x32_bf16(
                    afh[rt], bfh[ct], acc[rt][ct], 0, 0, 0);
                acc[rt][ct] = __builtin_amdgcn_mfma_f32_16x16x32_bf16(
                    afh[rt], bfl[ct], acc[rt][ct], 0, 0, 0);
                acc[rt][ct] = __builtin_amdgcn_mfma_f32_16x16x32_bf16(
                    afl[rt], bfh[ct], acc[rt][ct], 0, 0, 0);
            }
        __syncthreads();
    }

    #pragma unroll
    for (int rt = 0; rt < 4; ++rt)
        #pragma unroll
        for (int ct = 0; ct < 4; ++ct) {
            const int col = cb + wc * 64 + ct * 16 + lm;
            #pragma unroll
            for (int j = 0; j < 4; ++j) {
                const int row = i0 + wr * 64 + rt * 16 + lk * 4 + j;
                W[(size_t)row * 16384 + col] = acc[rt][ct][j];
            }
        }
}

// ---------------------------------------------------------------------------
// Batched 128x128 inverse — BLOCKED Gauss-Jordan, NB=4, NO pivoting.
// Round structure (2 barriers, NO serial section):
//   - extract own pivot-col float4 (15 static selects), swap halves via
//     __shfl_xor(·,1) (tid^1 = same row, other half) -> f in registers
//   - pivot-row threads publish raw rows R to LDS          -> B1
//   - ALL threads: read P (4 broadcast float4), adjugate-invert 4x4 in
//     registers (identical FP sequence on every thread => bit-identical
//     to the former tid0 version)
//   - rowstar[p][c] = (Pinv*R)[p][c] (+Pinv[p][c-4g] patch); wave-uniform
//     branch tid<128 handles p=0,1 else p=2,3 (static reg indices)  -> B2
//   - uniform rank-4 update a -= f_q * rowstar[q]; pivot-row threads patch
//     their own f (-1 at q==row&3) in registers.
// Double-buffered by round parity; 64 barriers total (was 96 + tid0 serial).
// ---------------------------------------------------------------------------
__global__ __launch_bounds__(256) void invert_kernel(
    const float* __restrict__ Om, float* __restrict__ Inv)
{
    const int n    = blockIdx.x;
    const int tid  = threadIdx.x;
    const int row  = tid >> 1;
    const int half = tid & 1;
    const size_t base = (size_t)n * (KK * KK);

    float4 a4[16];
    {
        const float4* src = (const float4*)(Om + base + (size_t)row * KK + half * 64);
        #pragma unroll
        for (int jj = 0; jj < 16; ++jj) a4[jj] = src[jj];
    }

    __shared__ __align__(16) float rowblk[2][4][132];
    __shared__ __align__(16) float rowstar[2][4][132];

    for (int g = 0; g < 32; ++g) {
        const int buf  = g & 1;
        const int hsel = g >> 4;
        const int gl   = g & 15;

        // ---- extract own float4 of pivot cols; exchange with sibling ----
        float4 e = a4[0];
        #pragma unroll
        for (int G = 1; G < 16; ++G) if (gl == G) e = a4[G];
        float4 o;
        o.x = __shfl_xor(e.x, 1);
        o.y = __shfl_xor(e.y, 1);
        o.z = __shfl_xor(e.z, 1);
        o.w = __shfl_xor(e.w, 1);
        float4 f = (half == hsel) ? e : o;
        // pivot-row threads patch own f: C[pivot] = P - I
        if ((row >> 2) == g) {
            const int p = row & 3;
            if (p == 0) f.x -= 1.0f;
            else if (p == 1) f.y -= 1.0f;
            else if (p == 2) f.z -= 1.0f;
            else f.w -= 1.0f;
        }
        // ---- publish raw pivot rows ----
        if ((row >> 2) == g) {
            const int p = row & 3;
            float* dst = &rowblk[buf][p][half * 64];
            #pragma unroll
            for (int jj = 0; jj < 16; ++jj)
                *(float4*)(dst + 4 * jj) = a4[jj];
        }
        __syncthreads();                                   // B1

        // ---- ALL threads: P (broadcast reads) -> Pinv in registers ----
        float4 p0 = *(const float4*)&rowblk[buf][0][4 * g];
        float4 p1 = *(const float4*)&rowblk[buf][1][4 * g];
        float4 p2 = *(const float4*)&rowblk[buf][2][4 * g];
        float4 p3 = *(const float4*)&rowblk[buf][3][4 * g];
        const float s0 = p0.x*p1.y - p1.x*p0.y;
        const float s1 = p0.x*p1.z - p1.x*p0.z;
        const float s2 = p0.x*p1.w - p1.x*p0.w;
        const float s3 = p0.y*p1.z - p1.y*p0.z;
        const float s4 = p0.y*p1.w - p1.y*p0.w;
        const float s5 = p0.z*p1.w - p1.z*p0.w;
        const float c5 = p2.z*p3.w - p3.z*p2.w;
        const float c4 = p2.y*p3.w - p3.y*p2.w;
        const float c3 = p2.y*p3.z - p3.y*p2.z;
        const float c2 = p2.x*p3.w - p3.x*p2.w;
        const float c1 = p2.x*p3.z - p3.x*p2.z;
        const float c0 = p2.x*p3.y - p3.x*p2.y;
        const float det = s0*c5 - s1*c4 + s2*c3 + s3*c2 - s4*c1 + s5*c0;
        const float id  = 1.0f / det;
        const float Pi00 = ( p1.y*c5 - p1.z*c4 + p1.w*c3) * id;
        const float Pi01 = (-p0.y*c5 + p0.z*c4 - p0.w*c3) * id;
        const float Pi02 = ( p3.y*s5 - p3.z*s4 + p3.w*s3) * id;
        const float Pi03 = (-p2.y*s5 + p2.z*s4 - p2.w*s3) * id;
        const float Pi10 = (-p1.x*c5 + p1.z*c2 - p1.w*c1) * id;
        const float Pi11 = ( p0.x*c5 - p0.z*c2 + p0.w*c1) * id;
        const float Pi12 = (-p3.x*s5 + p3.z*s2 - p3.w*s1) * id;
        const float Pi13 = ( p2.x*s5 - p2.z*s2 + p2.w*s1) * id;
        const float Pi20 = ( p1.x*c4 - p1.y*c2 + p1.w*c0) * id;
        const float Pi21 = (-p0.x*c4 + p0.y*c2 - p0.w*c0) * id;
        const float Pi22 = ( p3.x*s4 - p3.y*s2 + p3.w*s0) * id;
        const float Pi23 = (-p2.x*s4 + p2.y*s2 - p2.w*s0) * id;
        const float Pi30 = (-p1.x*c3 + p1.y*c1 - p1.z*c0) * id;
        const float Pi31 = ( p0.x*c3 - p0.y*c1 + p0.z*c0) * id;
        const float Pi32 = (-p3.x*s3 + p3.y*s1 - p3.z*s0) * id;
        const float Pi33 = ( p2.x*s3 - p2.y*s1 + p2.z*s0) * id;

        // ---- rowstar = Pinv * R (+ Pinv patch at pivot cols) ----
        {
            const int c = tid & 127;
            const float r0v = rowblk[buf][0][c];
            const float r1v = rowblk[buf][1][c];
            const float r2v = rowblk[buf][2][c];
            const float r3v = rowblk[buf][3][c];
            const int cl = c - 4 * g;
            if (tid < 128) {        // p = 0, 1  (wave-uniform branch)
                float v0 = Pi00*r0v + Pi01*r1v + Pi02*r2v + Pi03*r3v;
                float v1 = Pi10*r0v + Pi11*r1v + Pi12*r2v + Pi13*r3v;
                if      (cl == 0) { v0 += Pi00; v1 += Pi10; }
                else if (cl == 1) { v0 += Pi01; v1 += Pi11; }
                else if (cl == 2) { v0 += Pi02; v1 += Pi12; }
                else if (cl == 3) { v0 += Pi03; v1 += Pi13; }
                rowstar[buf][0][c] = v0;
                rowstar[buf][1][c] = v1;
            } else {                // p = 2, 3
                float v2 = Pi20*r0v + Pi21*r1v + Pi22*r2v + Pi23*r3v;
                float v3 = Pi30*r0v + Pi31*r1v + Pi32*r2v + Pi33*r3v;
                if      (cl == 0) { v2 += Pi20; v3 += Pi30; }
                else if (cl == 1) { v2 += Pi21; v3 += Pi31; }
                else if (cl == 2) { v2 += Pi22; v3 += Pi32; }
                else if (cl == 3) { v2 += Pi23; v3 += Pi33; }
                rowstar[buf][2][c] = v2;
                rowstar[buf][3][c] = v3;
            }
        }
        __syncthreads();                                   // B2

        // ---- uniform rank-4 update (all rows, fully static) ----
        const float4* rs0 = (const float4*)&rowstar[buf][0][half * 64];
        const float4* rs1 = (const float4*)&rowstar[buf][1][half * 64];
        const float4* rs2 = (const float4*)&rowstar[buf][2][half * 64];
        const float4* rs3 = (const float4*)&rowstar[buf][3][half * 64];
        #pragma unroll
        for (int jj = 0; jj < 16; ++jj) {
            const float4 r0 = rs0[jj], r1 = rs1[jj], r2 = rs2[jj], r3 = rs3[jj];
            a4[jj].x = fmaf(-f.x, r0.x, fmaf(-f.y, r1.x, fmaf(-f.z, r2.x, fmaf(-f.w, r3.x, a4[jj].x))));
            a4[jj].y = fmaf(-f.x, r0.y, fmaf(-f.y, r1.y, fmaf(-f.z, r2.y, fmaf(-f.w, r3.y, a4[jj].y))));
            a4[jj].z = fmaf(-f.x, r0.z, fmaf(-f.y, r1.z, fmaf(-f.z, r2.z, fmaf(-f.w, r3.z, a4[jj].z))));
            a4[jj].w = fmaf(-f.x, r0.w, fmaf(-f.y, r1.w, fmaf(-f.z, r2.w, fmaf(-f.w, r3.w, a4[jj].w))));
        }
        // no end barrier: LDS double-buffered by parity
    }

    float* dst = Inv + base + (size_t)row * KK + half * 64;
    #pragma unroll
    for (int jj = 0; jj < 16; ++jj) *(float4*)(dst + 4 * jj) = a4[jj];
}

// ---------------------------------------------------------------------------
extern "C" void kernel_launch(void* const* d_in, const int* in_sizes, int n_in,
                              void* d_out, int out_size, void* d_ws, size_t ws_size,
                              hipStream_t stream)
{
    const float* beta  = (const float*)d_in[0];
    const float* omega = (const float*)d_in[1];
    const float* Lp    = (const float*)d_in[2];
    const float* Lq    = (const float*)d_in[3];
    const float* obs   = (const float*)d_in[4];
    float* out = (float*)d_out;

    const size_t MATE = (size_t)NN * KK * KK;      // 16.8M elements (64 MB f32)

    float* S;
    unsigned short *Sth, *Stl;
    float* Wbuf;
    float* Inv;
    if (ws_size >= 2 * MATE * sizeof(float)) {
        S    = (float*)d_ws;
        Sth  = (unsigned short*)((char*)d_ws + MATE * sizeof(float));
        Stl  = Sth + MATE;
        Wbuf = out;
        Inv  = S;
    } else {
        S    = (float*)d_ws;
        Sth  = (unsigned short*)out;
        Stl  = Sth + MATE;
        Wbuf = (float*)d_ws;
        Inv  = out;
    }

    // 1. S_n = Omega_n^T Lq_n Omega_n
    sandwich_mfma<false><<<dim3(NN), dim3(256), 0, stream>>>(
        Lq, omega, S, nullptr, nullptr, nullptr, nullptr);
    // 2. split-transpose S -> Sth/Stl (bf16 [c][k])
    split_transpose_kernel<<<dim3(128, 8), dim3(256), 0, stream>>>(S, Sth, Stl);
    // 3. W = beta_nd @ S  (MFMA, split-bf16)
    gemm_beta_mfma<<<dim3(128, 8), dim3(256), 0, stream>>>(beta, Sth, Stl, Wbuf);
    // 4. Inv_n = Omega_n^{-1}
    invert_kernel<<<dim3(NN), dim3(256), 0, stream>>>(omega, Inv);
    // 5. M_n = Inv_n^T W_n Inv_n + Lp_n + colsum_n * Lq_n + obs
    sandwich_mfma<true><<<dim3(NN), dim3(256), 0, stream>>>(
        Wbuf, Inv, out, Lp, Lq, obs, beta);
}

// Round 8
// 451.170 us; speedup vs baseline: 1.1484x; 1.1484x over previous
//
#include <hip/hip_runtime.h>

#define NN 1024
#define KK 128

typedef __attribute__((ext_vector_type(8))) short bf16x8;
typedef __attribute__((ext_vector_type(4))) float f32x4;
typedef __attribute__((ext_vector_type(8))) unsigned short u16x8;

__device__ __forceinline__ unsigned int bf16rne(float x) {
    unsigned int u = __float_as_uint(x);
    return (u + 0x7FFFu + ((u >> 16) & 1u)) >> 16;
}

__device__ __forceinline__ void split8(const float* xs, bf16x8& h8, bf16x8& l8) {
    #pragma unroll
    for (int j = 0; j < 8; ++j) {
        unsigned int hb = bf16rne(xs[j]);
        float hf = __uint_as_float(hb << 16);
        h8[j] = (short)hb;
        l8[j] = (short)bf16rne(xs[j] - hf);
    }
}

// ---------------------------------------------------------------------------
// MFMA sandwich: Out_n = B_n^T (A_n B_n)  [+ epilogue for FINAL], split-bf16.
// (unchanged from round 6)
// ---------------------------------------------------------------------------
template<bool FINAL>
__global__ __launch_bounds__(256) void sandwich_mfma(
    const float* __restrict__ A_, const float* __restrict__ B_,
    float* __restrict__ Out,
    const float* __restrict__ Lp, const float* __restrict__ Lq,
    const float* __restrict__ obs, const float* __restrict__ beta)
{
    __shared__ short lds_buf[69632];
    short* Bth = lds_buf;
    short* Btl = lds_buf + 17408;
    short* Tth = lds_buf + 34816;
    short* Ttl = lds_buf + 52224;
    float* pan = (float*)(lds_buf + 34816);
    __shared__ float wred[4];
    __shared__ float cs_sh;

    const int n    = blockIdx.x;
    const int tid  = threadIdx.x;
    const int lane = tid & 63;
    const int wid  = tid >> 6;
    const int wr   = wid >> 1, wc = wid & 1;
    const int lm   = lane & 15;
    const int lk   = lane >> 4;
    const size_t base = (size_t)n * (KK * KK);

    if (FINAL) {
        float s = 0.f;
        for (int j = tid; j < NN; j += 256)
            if (j != n) s += beta[(size_t)j * NN + n];
        #pragma unroll
        for (int off = 32; off >= 1; off >>= 1) s += __shfl_down(s, off);
        if ((tid & 63) == 0) wred[tid >> 6] = s;
        __syncthreads();
        if (tid == 0) cs_sh = wred[0] + wred[1] + wred[2] + wred[3];
    }

    // ---- stage Bt = B^T (hi/lo bf16) via two 64-col f32 panels ----
    #pragma unroll
    for (int cp = 0; cp < 2; ++cp) {
        #pragma unroll
        for (int it = 0; it < 8; ++it) {
            int gid = it * 256 + tid;
            int k   = gid >> 4;
            int c4  = (gid & 15) * 4;
            *(float4*)&pan[k * 66 + c4] =
                *(const float4*)(B_ + base + (size_t)k * KK + cp * 64 + c4);
        }
        __syncthreads();
        #pragma unroll
        for (int it = 0; it < 4; ++it) {
            int t  = it * 256 + tid;
            int c  = t >> 4;
            int ko = (t & 15) * 8;
            float xs[8];
            #pragma unroll
            for (int j = 0; j < 8; ++j) xs[j] = pan[(ko + j) * 66 + c];
            bf16x8 h8, l8;
            split8(xs, h8, l8);
            const int gc = cp * 64 + c;
            *(bf16x8*)&Bth[gc * 136 + ko] = h8;
            *(bf16x8*)&Btl[gc * 136 + ko] = l8;
        }
        __syncthreads();
    }

    // ================= stage 1: T = A @ B =================
    f32x4 acc[4][4];
    #pragma unroll
    for (int a = 0; a < 4; ++a)
        #pragma unroll
        for (int b = 0; b < 4; ++b) acc[a][b] = (f32x4){0.f, 0.f, 0.f, 0.f};

    #pragma unroll 1
    for (int ks = 0; ks < 4; ++ks) {
        const int k0 = ks * 32;
        bf16x8 afh[4], afl[4], bfh[4], bfl[4];
        #pragma unroll
        for (int rt = 0; rt < 4; ++rt) {
            const int r = wr * 64 + rt * 16 + lm;
            const float* ap = A_ + base + (size_t)r * KK + k0 + lk * 8;
            float4 x0 = *(const float4*)ap;
            float4 x1 = *(const float4*)(ap + 4);
            float xs[8] = {x0.x, x0.y, x0.z, x0.w, x1.x, x1.y, x1.z, x1.w};
            split8(xs, afh[rt], afl[rt]);
        }
        #pragma unroll
        for (int ct = 0; ct < 4; ++ct) {
            const int c = wc * 64 + ct * 16 + lm;
            bfh[ct] = *(const bf16x8*)&Bth[c * 136 + k0 + lk * 8];
            bfl[ct] = *(const bf16x8*)&Btl[c * 136 + k0 + lk * 8];
        }
        #pragma unroll
        for (int rt = 0; rt < 4; ++rt)
            #pragma unroll
            for (int ct = 0; ct < 4; ++ct) {
                acc[rt][ct] = __builtin_amdgcn_mfma_f32_16x16x32_bf16(
                    afh[rt], bfh[ct], acc[rt][ct], 0, 0, 0);
                acc[rt][ct] = __builtin_amdgcn_mfma_f32_16x16x32_bf16(
                    afh[rt], bfl[ct], acc[rt][ct], 0, 0, 0);
                acc[rt][ct] = __builtin_amdgcn_mfma_f32_16x16x32_bf16(
                    afl[rt], bfh[ct], acc[rt][ct], 0, 0, 0);
            }
    }

    // ---- T -> Tt[c][k] hi/lo ----
    #pragma unroll
    for (int rt = 0; rt < 4; ++rt)
        #pragma unroll
        for (int ct = 0; ct < 4; ++ct) {
            const int col  = wc * 64 + ct * 16 + lm;
            const int row0 = wr * 64 + rt * 16 + lk * 4;
            unsigned short h[4], l[4];
            #pragma unroll
            for (int j = 0; j < 4; ++j) {
                float x = acc[rt][ct][j];
                unsigned int hb = bf16rne(x);
                h[j] = (unsigned short)hb;
                l[j] = (unsigned short)bf16rne(x - __uint_as_float(hb << 16));
            }
            *(ushort4*)&Tth[col * 136 + row0] = make_ushort4(h[0], h[1], h[2], h[3]);
            *(ushort4*)&Ttl[col * 136 + row0] = make_ushort4(l[0], l[1], l[2], l[3]);
        }
    __syncthreads();

    // ================= stage 2: Out = B^T @ T =================
    f32x4 acc2[4][4];
    #pragma unroll
    for (int a = 0; a < 4; ++a)
        #pragma unroll
        for (int b = 0; b < 4; ++b) acc2[a][b] = (f32x4){0.f, 0.f, 0.f, 0.f};

    #pragma unroll 1
    for (int ks = 0; ks < 4; ++ks) {
        const int k0 = ks * 32;
        bf16x8 afh[4], afl[4], bfh[4], bfl[4];
        #pragma unroll
        for (int rt = 0; rt < 4; ++rt) {
            const int r = wr * 64 + rt * 16 + lm;
            afh[rt] = *(const bf16x8*)&Bth[r * 136 + k0 + lk * 8];
            afl[rt] = *(const bf16x8*)&Btl[r * 136 + k0 + lk * 8];
        }
        #pragma unroll
        for (int ct = 0; ct < 4; ++ct) {
            const int c = wc * 64 + ct * 16 + lm;
            bfh[ct] = *(const bf16x8*)&Tth[c * 136 + k0 + lk * 8];
            bfl[ct] = *(const bf16x8*)&Ttl[c * 136 + k0 + lk * 8];
        }
        #pragma unroll
        for (int rt = 0; rt < 4; ++rt)
            #pragma unroll
            for (int ct = 0; ct < 4; ++ct) {
                acc2[rt][ct] = __builtin_amdgcn_mfma_f32_16x16x32_bf16(
                    afh[rt], bfh[ct], acc2[rt][ct], 0, 0, 0);
                acc2[rt][ct] = __builtin_amdgcn_mfma_f32_16x16x32_bf16(
                    afh[rt], bfl[ct], acc2[rt][ct], 0, 0, 0);
                acc2[rt][ct] = __builtin_amdgcn_mfma_f32_16x16x32_bf16(
                    afl[rt], bfh[ct], acc2[rt][ct], 0, 0, 0);
            }
    }

    // ================= epilogue + store =================
    const float csv = FINAL ? cs_sh : 0.f;
    #pragma unroll
    for (int rt = 0; rt < 4; ++rt)
        #pragma unroll
        for (int ct = 0; ct < 4; ++ct) {
            const int col  = wc * 64 + ct * 16 + lm;
            const int row0 = wr * 64 + rt * 16 + lk * 4;
            #pragma unroll
            for (int j = 0; j < 4; ++j) {
                const int row = row0 + j;
                float o = acc2[rt][ct][j];
                if (FINAL) {
                    o += Lp[base + (size_t)row * KK + col]
                       + csv * Lq[base + (size_t)row * KK + col]
                       + obs[(size_t)row * KK + col];
                }
                Out[base + (size_t)row * KK + col] = o;
            }
        }
}

// ---------------------------------------------------------------------------
// Split-transpose: S (f32, [1024][16384]) -> Sth/Stl (bf16, [16384][1024]).
// ---------------------------------------------------------------------------
__global__ __launch_bounds__(256) void split_transpose_kernel(
    const float* __restrict__ S,
    unsigned short* __restrict__ Th, unsigned short* __restrict__ Tl)
{
    __shared__ float tile[128][132];
    const int tid = threadIdx.x;
    const int c0  = blockIdx.x * 128;
    const int k0  = blockIdx.y * 128;

    #pragma unroll
    for (int it = 0; it < 16; ++it) {
        int gid = it * 256 + tid;
        int kk  = gid >> 5;
        int c4  = (gid & 31) * 4;
        float4 v = *(const float4*)(S + (size_t)(k0 + kk) * 16384 + c0 + c4);
        *(float4*)&tile[kk][c4] = v;
    }
    __syncthreads();
    #pragma unroll
    for (int it = 0; it < 8; ++it) {
        int gid = it * 256 + tid;
        int c   = gid >> 4;
        int kc  = (gid & 15) * 8;
        u16x8 h, l;
        #pragma unroll
        for (int j = 0; j < 8; ++j) {
            float x = tile[kc + j][c];
            unsigned int hb = bf16rne(x);
            float hf = __uint_as_float(hb << 16);
            h[j] = (unsigned short)hb;
            l[j] = (unsigned short)bf16rne(x - hf);
        }
        size_t o = (size_t)(c0 + c) * 1024 + k0 + kc;
        *(u16x8*)(Th + o) = h;
        *(u16x8*)(Tl + o) = l;
    }
}

// ---------------------------------------------------------------------------
// Big GEMM via MFMA, split-bf16 (unchanged from round 5/6).
// ---------------------------------------------------------------------------
__global__ __launch_bounds__(256) void gemm_beta_mfma(
    const float* __restrict__ beta,
    const unsigned short* __restrict__ Sth,
    const unsigned short* __restrict__ Stl,
    float* __restrict__ W)
{
    __shared__ unsigned short Ah[128][40], Al[128][40];
    __shared__ unsigned short Bh[128][40], Bl[128][40];

    const int tid  = threadIdx.x;
    const int lane = tid & 63;
    const int wid  = tid >> 6;
    const int wr   = wid >> 1, wc = wid & 1;
    const int lm   = lane & 15;
    const int lk   = lane >> 4;
    const int i0   = blockIdx.y * 128;
    const int cb   = blockIdx.x * 128;

    f32x4 acc[4][4];
    #pragma unroll
    for (int a = 0; a < 4; ++a)
        #pragma unroll
        for (int b = 0; b < 4; ++b) acc[a][b] = (f32x4){0.f, 0.f, 0.f, 0.f};

    for (int k0 = 0; k0 < 1024; k0 += 32) {
        #pragma unroll
        for (int it = 0; it < 4; ++it) {
            int gid = it * 256 + tid;
            int r   = gid >> 3;
            int c4  = (gid & 7) * 4;
            int gi  = i0 + r;
            float4 v = *(const float4*)(beta + (size_t)gi * NN + k0 + c4);
            if (gi == k0 + c4 + 0) v.x = 0.f;
            if (gi == k0 + c4 + 1) v.y = 0.f;
            if (gi == k0 + c4 + 2) v.z = 0.f;
            if (gi == k0 + c4 + 3) v.w = 0.f;
            float xs[4] = {v.x, v.y, v.z, v.w};
            unsigned short hs[4], ls[4];
            #pragma unroll
            for (int j = 0; j < 4; ++j) {
                unsigned int hb = bf16rne(xs[j]);
                hs[j] = (unsigned short)hb;
                ls[j] = (unsigned short)bf16rne(xs[j] - __uint_as_float(hb << 16));
            }
            *(ushort4*)&Ah[r][c4] = make_ushort4(hs[0], hs[1], hs[2], hs[3]);
            *(ushort4*)&Al[r][c4] = make_ushort4(ls[0], ls[1], ls[2], ls[3]);
        }
        #pragma unroll
        for (int it = 0; it < 2; ++it) {
            int gid = it * 256 + tid;
            int c   = gid >> 2;
            int kc  = (gid & 3) * 8;
            size_t o = (size_t)(cb + c) * 1024 + k0 + kc;
            *(u16x8*)&Bh[c][kc] = *(const u16x8*)(Sth + o);
            *(u16x8*)&Bl[c][kc] = *(const u16x8*)(Stl + o);
        }
        __syncthreads();

        bf16x8 afh[4], afl[4], bfh[4], bfl[4];
        #pragma unroll
        for (int rt = 0; rt < 4; ++rt) {
            const int r = wr * 64 + rt * 16 + lm;
            afh[rt] = *(const bf16x8*)&Ah[r][lk * 8];
            afl[rt] = *(const bf16x8*)&Al[r][lk * 8];
        }
        #pragma unroll
        for (int ct = 0; ct < 4; ++ct) {
            const int c = wc * 64 + ct * 16 + lm;
            bfh[ct] = *(const bf16x8*)&Bh[c][lk * 8];
            bfl[ct] = *(const bf16x8*)&Bl[c][lk * 8];
        }
        #pragma unroll
        for (int rt = 0; rt < 4; ++rt)
            #pragma unroll
            for (int ct = 0; ct < 4; ++ct) {
                acc[rt][ct] = __builtin_amdgcn_mfma_f32_16x16x32_bf16(
                    afh[rt], bfh[ct], acc[rt][ct], 0, 0, 0);
                acc[rt][ct] = __builtin_amdgcn_mfma_f32_16x16x32_bf16(
                    afh[rt], bfl[ct], acc[rt][ct], 0, 0, 0);
                acc[rt][ct] = __builtin_amdgcn_mfma_f32_16x16x32_bf16(
                    afl[rt], bfh[ct], acc[rt][ct], 0, 0, 0);
            }
        __syncthreads();
    }

    #pragma unroll
    for (int rt = 0; rt < 4; ++rt)
        #pragma unroll
        for (int ct = 0; ct < 4; ++ct) {
            const int col = cb + wc * 64 + ct * 16 + lm;
            #pragma unroll
            for (int j = 0; j < 4; ++j) {
                const int row = i0 + wr * 64 + rt * 16 + lk * 4 + j;
                W[(size_t)row * 16384 + col] = acc[rt][ct][j];
            }
        }
}

// ---------------------------------------------------------------------------
// Batched 128x128 inverse — BLOCKED Gauss-Jordan, NB=4, NO pivoting.
// NEW thread mapping: thread (rg,cg) owns an 8x8 tile (rows rg*8.., cols
// cg*8..) => rowstar read per round drops 64 -> 8 b128 (reused over 8 rows);
// f comes from a small cpan LDS panel (8 b128) + P broadcast (4 b128):
// ~20 b128/thread/round vs 64+ before (LDS return-BW was the bottleneck).
// Pivot block g: rows/cols 4g..4g+3, owner group pg = g>>1, half sub = g&1
// (static register indices via the uniform sub branch).
// FP math is bit-identical to round 7 (same adjugate, same rowstar
// assignment, same fmaf nesting q3->q0).
// ---------------------------------------------------------------------------
__global__ __launch_bounds__(256) void invert_kernel(
    const float* __restrict__ Om, float* __restrict__ Inv)
{
    const int n   = blockIdx.x;
    const int tid = threadIdx.x;
    const int rg  = tid >> 4;        // 0..15: row group (8 rows)
    const int cg  = tid & 15;        // 0..15: col group (8 cols)
    const int r0  = rg * 8;
    const int c0  = cg * 8;
    const size_t base = (size_t)n * (KK * KK);

    float4 a4[8][2];                 // 8 rows x 8 cols
    #pragma unroll
    for (int i = 0; i < 8; ++i) {
        const float* src = Om + base + (size_t)(r0 + i) * KK + c0;
        a4[i][0] = *(const float4*)(src);
        a4[i][1] = *(const float4*)(src + 4);
    }

    __shared__ __align__(16) float rowblk[2][4][132];   // raw pivot rows R
    __shared__ __align__(16) float rowstar[2][4][132];  // Pinv*R (patched)
    __shared__ __align__(16) float cpan[2][128][4];     // C panel: [row][q]

    for (int g = 0; g < 32; ++g) {
        const int buf = g & 1;
        const int pg  = g >> 1;      // owner group of pivot rows AND cols
        const int sub = g & 1;       // which half of the owner's 8

        // ---- publish raw pivot rows (rows 4g..4g+3 = local sub*4..+3) ----
        if (rg == pg) {
            if (sub == 0) {
                #pragma unroll
                for (int p = 0; p < 4; ++p) {
                    *(float4*)&rowblk[buf][p][c0]     = a4[p][0];
                    *(float4*)&rowblk[buf][p][c0 + 4] = a4[p][1];
                }
            } else {
                #pragma unroll
                for (int p = 0; p < 4; ++p) {
                    *(float4*)&rowblk[buf][p][c0]     = a4[4 + p][0];
                    *(float4*)&rowblk[buf][p][c0 + 4] = a4[4 + p][1];
                }
            }
        }
        // ---- publish C panel (cols 4g..4g+3 = local float4 index sub) ----
        if (cg == pg) {
            if (sub == 0) {
                #pragma unroll
                for (int i = 0; i < 8; ++i)
                    *(float4*)&cpan[buf][r0 + i][0] = a4[i][0];
            } else {
                #pragma unroll
                for (int i = 0; i < 8; ++i)
                    *(float4*)&cpan[buf][r0 + i][0] = a4[i][1];
            }
        }
        __syncthreads();                                   // B1

        // ---- ALL threads: P (broadcast reads) -> Pinv in registers ----
        float4 p0 = *(const float4*)&rowblk[buf][0][4 * g];
        float4 p1 = *(const float4*)&rowblk[buf][1][4 * g];
        float4 p2 = *(const float4*)&rowblk[buf][2][4 * g];
        float4 p3 = *(const float4*)&rowblk[buf][3][4 * g];
        const float s0 = p0.x*p1.y - p1.x*p0.y;
        const float s1 = p0.x*p1.z - p1.x*p0.z;
        const float s2 = p0.x*p1.w - p1.x*p0.w;
        const float s3 = p0.y*p1.z - p1.y*p0.z;
        const float s4 = p0.y*p1.w - p1.y*p0.w;
        const float s5 = p0.z*p1.w - p1.z*p0.w;
        const float c5 = p2.z*p3.w - p3.z*p2.w;
        const float c4 = p2.y*p3.w - p3.y*p2.w;
        const float c3 = p2.y*p3.z - p3.y*p2.z;
        const float c2 = p2.x*p3.w - p3.x*p2.w;
        const float c1 = p2.x*p3.z - p3.x*p2.z;
        const float c0f = p2.x*p3.y - p3.x*p2.y;
        const float det = s0*c5 - s1*c4 + s2*c3 + s3*c2 - s4*c1 + s5*c0f;
        const float id  = 1.0f / det;
        const float Pi00 = ( p1.y*c5 - p1.z*c4 + p1.w*c3) * id;
        const float Pi01 = (-p0.y*c5 + p0.z*c4 - p0.w*c3) * id;
        const float Pi02 = ( p3.y*s5 - p3.z*s4 + p3.w*s3) * id;
        const float Pi03 = (-p2.y*s5 + p2.z*s4 - p2.w*s3) * id;
        const float Pi10 = (-p1.x*c5 + p1.z*c2 - p1.w*c1) * id;
        const float Pi11 = ( p0.x*c5 - p0.z*c2 + p0.w*c1) * id;
        const float Pi12 = (-p3.x*s5 + p3.z*s2 - p3.w*s1) * id;
        const float Pi13 = ( p2.x*s5 - p2.z*s2 + p2.w*s1) * id;
        const float Pi20 = ( p1.x*c4 - p1.y*c2 + p1.w*c0f) * id;
        const float Pi21 = (-p0.x*c4 + p0.y*c2 - p0.w*c0f) * id;
        const float Pi22 = ( p3.x*s4 - p3.y*s2 + p3.w*s0) * id;
        const float Pi23 = (-p2.x*s4 + p2.y*s2 - p2.w*s0) * id;
        const float Pi30 = (-p1.x*c3 + p1.y*c1 - p1.z*c0f) * id;
        const float Pi31 = ( p0.x*c3 - p0.y*c1 + p0.z*c0f) * id;
        const float Pi32 = (-p3.x*s3 + p3.y*s1 - p3.z*s0) * id;
        const float Pi33 = ( p2.x*s3 - p2.y*s1 + p2.z*s0) * id;

        // ---- rowstar = Pinv * R (+ Pinv patch at pivot cols) ----
        {
            const int c = tid & 127;
            const float r0v = rowblk[buf][0][c];
            const float r1v = rowblk[buf][1][c];
            const float r2v = rowblk[buf][2][c];
            const float r3v = rowblk[buf][3][c];
            const int cl = c - 4 * g;
            if (tid < 128) {        // p = 0, 1
                float v0 = Pi00*r0v + Pi01*r1v + Pi02*r2v + Pi03*r3v;
                float v1 = Pi10*r0v + Pi11*r1v + Pi12*r2v + Pi13*r3v;
                if      (cl == 0) { v0 += Pi00; v1 += Pi10; }
                else if (cl == 1) { v0 += Pi01; v1 += Pi11; }
                else if (cl == 2) { v0 += Pi02; v1 += Pi12; }
                else if (cl == 3) { v0 += Pi03; v1 += Pi13; }
                rowstar[buf][0][c] = v0;
                rowstar[buf][1][c] = v1;
            } else {                // p = 2, 3
                float v2 = Pi20*r0v + Pi21*r1v + Pi22*r2v + Pi23*r3v;
                float v3 = Pi30*r0v + Pi31*r1v + Pi32*r2v + Pi33*r3v;
                if      (cl == 0) { v2 += Pi20; v3 += Pi30; }
                else if (cl == 1) { v2 += Pi21; v3 += Pi31; }
                else if (cl == 2) { v2 += Pi22; v3 += Pi32; }
                else if (cl == 3) { v2 += Pi23; v3 += Pi33; }
                rowstar[buf][2][c] = v2;
                rowstar[buf][3][c] = v3;
            }
        }
        __syncthreads();                                   // B2

        // ---- read own rowstar slice once (reused across 8 rows) ----
        float4 rs0a = *(const float4*)&rowstar[buf][0][c0];
        float4 rs0b = *(const float4*)&rowstar[buf][0][c0 + 4];
        float4 rs1a = *(const float4*)&rowstar[buf][1][c0];
        float4 rs1b = *(const float4*)&rowstar[buf][1][c0 + 4];
        float4 rs2a = *(const float4*)&rowstar[buf][2][c0];
        float4 rs2b = *(const float4*)&rowstar[buf][2][c0 + 4];
        float4 rs3a = *(const float4*)&rowstar[buf][3][c0];
        float4 rs3b = *(const float4*)&rowstar[buf][3][c0 + 4];

        // ---- uniform rank-4 update, f streamed per row ----
        const bool piv_rg = (rg == pg);
        #pragma unroll
        for (int i = 0; i < 8; ++i) {
            float4 f = *(const float4*)&cpan[buf][r0 + i][0];
            // pivot rows patch: C[pivot] = P - I (local rows sub*4..+3)
            if (piv_rg) {
                if (sub == 0) {
                    if (i == 0) f.x -= 1.0f;
                    if (i == 1) f.y -= 1.0f;
                    if (i == 2) f.z -= 1.0f;
                    if (i == 3) f.w -= 1.0f;
                } else {
                    if (i == 4) f.x -= 1.0f;
                    if (i == 5) f.y -= 1.0f;
                    if (i == 6) f.z -= 1.0f;
                    if (i == 7) f.w -= 1.0f;
                }
            }
            a4[i][0].x = fmaf(-f.x, rs0a.x, fmaf(-f.y, rs1a.x, fmaf(-f.z, rs2a.x, fmaf(-f.w, rs3a.x, a4[i][0].x))));
            a4[i][0].y = fmaf(-f.x, rs0a.y, fmaf(-f.y, rs1a.y, fmaf(-f.z, rs2a.y, fmaf(-f.w, rs3a.y, a4[i][0].y))));
            a4[i][0].z = fmaf(-f.x, rs0a.z, fmaf(-f.y, rs1a.z, fmaf(-f.z, rs2a.z, fmaf(-f.w, rs3a.z, a4[i][0].z))));
            a4[i][0].w = fmaf(-f.x, rs0a.w, fmaf(-f.y, rs1a.w, fmaf(-f.z, rs2a.w, fmaf(-f.w, rs3a.w, a4[i][0].w))));
            a4[i][1].x = fmaf(-f.x, rs0b.x, fmaf(-f.y, rs1b.x, fmaf(-f.z, rs2b.x, fmaf(-f.w, rs3b.x, a4[i][1].x))));
            a4[i][1].y = fmaf(-f.x, rs0b.y, fmaf(-f.y, rs1b.y, fmaf(-f.z, rs2b.y, fmaf(-f.w, rs3b.y, a4[i][1].y))));
            a4[i][1].z = fmaf(-f.x, rs0b.z, fmaf(-f.y, rs1b.z, fmaf(-f.z, rs2b.z, fmaf(-f.w, rs3b.z, a4[i][1].z))));
            a4[i][1].w = fmaf(-f.x, rs0b.w, fmaf(-f.y, rs1b.w, fmaf(-f.z, rs2b.w, fmaf(-f.w, rs3b.w, a4[i][1].w))));
        }
        // no end barrier: LDS double-buffered by parity
    }

    #pragma unroll
    for (int i = 0; i < 8; ++i) {
        float* dst = Inv + base + (size_t)(r0 + i) * KK + c0;
        *(float4*)(dst)     = a4[i][0];
        *(float4*)(dst + 4) = a4[i][1];
    }
}

// ---------------------------------------------------------------------------
extern "C" void kernel_launch(void* const* d_in, const int* in_sizes, int n_in,
                              void* d_out, int out_size, void* d_ws, size_t ws_size,
                              hipStream_t stream)
{
    const float* beta  = (const float*)d_in[0];
    const float* omega = (const float*)d_in[1];
    const float* Lp    = (const float*)d_in[2];
    const float* Lq    = (const float*)d_in[3];
    const float* obs   = (const float*)d_in[4];
    float* out = (float*)d_out;

    const size_t MATE = (size_t)NN * KK * KK;      // 16.8M elements (64 MB f32)

    float* S;
    unsigned short *Sth, *Stl;
    float* Wbuf;
    float* Inv;
    if (ws_size >= 2 * MATE * sizeof(float)) {
        S    = (float*)d_ws;
        Sth  = (unsigned short*)((char*)d_ws + MATE * sizeof(float));
        Stl  = Sth + MATE;
        Wbuf = out;
        Inv  = S;
    } else {
        S    = (float*)d_ws;
        Sth  = (unsigned short*)out;
        Stl  = Sth + MATE;
        Wbuf = (float*)d_ws;
        Inv  = out;
    }

    // 1. S_n = Omega_n^T Lq_n Omega_n
    sandwich_mfma<false><<<dim3(NN), dim3(256), 0, stream>>>(
        Lq, omega, S, nullptr, nullptr, nullptr, nullptr);
    // 2. split-transpose S -> Sth/Stl (bf16 [c][k])
    split_transpose_kernel<<<dim3(128, 8), dim3(256), 0, stream>>>(S, Sth, Stl);
    // 3. W = beta_nd @ S  (MFMA, split-bf16)
    gemm_beta_mfma<<<dim3(128, 8), dim3(256), 0, stream>>>(beta, Sth, Stl, Wbuf);
    // 4. Inv_n = Omega_n^{-1}
    invert_kernel<<<dim3(NN), dim3(256), 0, stream>>>(omega, Inv);
    // 5. M_n = Inv_n^T W_n Inv_n + Lp_n + colsum_n * Lq_n + obs
    sandwich_mfma<true><<<dim3(NN), dim3(256), 0, stream>>>(
        Wbuf, Inv, out, Lp, Lq, obs, beta);
}

// Round 9
// 431.675 us; speedup vs baseline: 1.2003x; 1.0452x over previous
//
#include <hip/hip_runtime.h>

#define NN 1024
#define KK 128

typedef __attribute__((ext_vector_type(8))) short bf16x8;
typedef __attribute__((ext_vector_type(4))) float f32x4;
typedef __attribute__((ext_vector_type(8))) unsigned short u16x8;

__device__ __forceinline__ unsigned int bf16rne(float x) {
    unsigned int u = __float_as_uint(x);
    return (u + 0x7FFFu + ((u >> 16) & 1u)) >> 16;
}

__device__ __forceinline__ void split8(const float* xs, bf16x8& h8, bf16x8& l8) {
    #pragma unroll
    for (int j = 0; j < 8; ++j) {
        unsigned int hb = bf16rne(xs[j]);
        float hf = __uint_as_float(hb << 16);
        h8[j] = (short)hb;
        l8[j] = (short)bf16rne(xs[j] - hf);
    }
}

// ---------------------------------------------------------------------------
// MFMA sandwich: Out_n = B_n^T (A_n B_n)  [+ epilogue for FINAL], split-bf16.
// (unchanged from round 6)
// ---------------------------------------------------------------------------
template<bool FINAL>
__global__ __launch_bounds__(256) void sandwich_mfma(
    const float* __restrict__ A_, const float* __restrict__ B_,
    float* __restrict__ Out,
    const float* __restrict__ Lp, const float* __restrict__ Lq,
    const float* __restrict__ obs, const float* __restrict__ beta)
{
    __shared__ short lds_buf[69632];
    short* Bth = lds_buf;
    short* Btl = lds_buf + 17408;
    short* Tth = lds_buf + 34816;
    short* Ttl = lds_buf + 52224;
    float* pan = (float*)(lds_buf + 34816);
    __shared__ float wred[4];
    __shared__ float cs_sh;

    const int n    = blockIdx.x;
    const int tid  = threadIdx.x;
    const int lane = tid & 63;
    const int wid  = tid >> 6;
    const int wr   = wid >> 1, wc = wid & 1;
    const int lm   = lane & 15;
    const int lk   = lane >> 4;
    const size_t base = (size_t)n * (KK * KK);

    if (FINAL) {
        float s = 0.f;
        for (int j = tid; j < NN; j += 256)
            if (j != n) s += beta[(size_t)j * NN + n];
        #pragma unroll
        for (int off = 32; off >= 1; off >>= 1) s += __shfl_down(s, off);
        if ((tid & 63) == 0) wred[tid >> 6] = s;
        __syncthreads();
        if (tid == 0) cs_sh = wred[0] + wred[1] + wred[2] + wred[3];
    }

    // ---- stage Bt = B^T (hi/lo bf16) via two 64-col f32 panels ----
    #pragma unroll
    for (int cp = 0; cp < 2; ++cp) {
        #pragma unroll
        for (int it = 0; it < 8; ++it) {
            int gid = it * 256 + tid;
            int k   = gid >> 4;
            int c4  = (gid & 15) * 4;
            *(float4*)&pan[k * 66 + c4] =
                *(const float4*)(B_ + base + (size_t)k * KK + cp * 64 + c4);
        }
        __syncthreads();
        #pragma unroll
        for (int it = 0; it < 4; ++it) {
            int t  = it * 256 + tid;
            int c  = t >> 4;
            int ko = (t & 15) * 8;
            float xs[8];
            #pragma unroll
            for (int j = 0; j < 8; ++j) xs[j] = pan[(ko + j) * 66 + c];
            bf16x8 h8, l8;
            split8(xs, h8, l8);
            const int gc = cp * 64 + c;
            *(bf16x8*)&Bth[gc * 136 + ko] = h8;
            *(bf16x8*)&Btl[gc * 136 + ko] = l8;
        }
        __syncthreads();
    }

    // ================= stage 1: T = A @ B =================
    f32x4 acc[4][4];
    #pragma unroll
    for (int a = 0; a < 4; ++a)
        #pragma unroll
        for (int b = 0; b < 4; ++b) acc[a][b] = (f32x4){0.f, 0.f, 0.f, 0.f};

    #pragma unroll 1
    for (int ks = 0; ks < 4; ++ks) {
        const int k0 = ks * 32;
        bf16x8 afh[4], afl[4], bfh[4], bfl[4];
        #pragma unroll
        for (int rt = 0; rt < 4; ++rt) {
            const int r = wr * 64 + rt * 16 + lm;
            const float* ap = A_ + base + (size_t)r * KK + k0 + lk * 8;
            float4 x0 = *(const float4*)ap;
            float4 x1 = *(const float4*)(ap + 4);
            float xs[8] = {x0.x, x0.y, x0.z, x0.w, x1.x, x1.y, x1.z, x1.w};
            split8(xs, afh[rt], afl[rt]);
        }
        #pragma unroll
        for (int ct = 0; ct < 4; ++ct) {
            const int c = wc * 64 + ct * 16 + lm;
            bfh[ct] = *(const bf16x8*)&Bth[c * 136 + k0 + lk * 8];
            bfl[ct] = *(const bf16x8*)&Btl[c * 136 + k0 + lk * 8];
        }
        #pragma unroll
        for (int rt = 0; rt < 4; ++rt)
            #pragma unroll
            for (int ct = 0; ct < 4; ++ct) {
                acc[rt][ct] = __builtin_amdgcn_mfma_f32_16x16x32_bf16(
                    afh[rt], bfh[ct], acc[rt][ct], 0, 0, 0);
                acc[rt][ct] = __builtin_amdgcn_mfma_f32_16x16x32_bf16(
                    afh[rt], bfl[ct], acc[rt][ct], 0, 0, 0);
                acc[rt][ct] = __builtin_amdgcn_mfma_f32_16x16x32_bf16(
                    afl[rt], bfh[ct], acc[rt][ct], 0, 0, 0);
            }
    }

    // ---- T -> Tt[c][k] hi/lo ----
    #pragma unroll
    for (int rt = 0; rt < 4; ++rt)
        #pragma unroll
        for (int ct = 0; ct < 4; ++ct) {
            const int col  = wc * 64 + ct * 16 + lm;
            const int row0 = wr * 64 + rt * 16 + lk * 4;
            unsigned short h[4], l[4];
            #pragma unroll
            for (int j = 0; j < 4; ++j) {
                float x = acc[rt][ct][j];
                unsigned int hb = bf16rne(x);
                h[j] = (unsigned short)hb;
                l[j] = (unsigned short)bf16rne(x - __uint_as_float(hb << 16));
            }
            *(ushort4*)&Tth[col * 136 + row0] = make_ushort4(h[0], h[1], h[2], h[3]);
            *(ushort4*)&Ttl[col * 136 + row0] = make_ushort4(l[0], l[1], l[2], l[3]);
        }
    __syncthreads();

    // ================= stage 2: Out = B^T @ T =================
    f32x4 acc2[4][4];
    #pragma unroll
    for (int a = 0; a < 4; ++a)
        #pragma unroll
        for (int b = 0; b < 4; ++b) acc2[a][b] = (f32x4){0.f, 0.f, 0.f, 0.f};

    #pragma unroll 1
    for (int ks = 0; ks < 4; ++ks) {
        const int k0 = ks * 32;
        bf16x8 afh[4], afl[4], bfh[4], bfl[4];
        #pragma unroll
        for (int rt = 0; rt < 4; ++rt) {
            const int r = wr * 64 + rt * 16 + lm;
            afh[rt] = *(const bf16x8*)&Bth[r * 136 + k0 + lk * 8];
            afl[rt] = *(const bf16x8*)&Btl[r * 136 + k0 + lk * 8];
        }
        #pragma unroll
        for (int ct = 0; ct < 4; ++ct) {
            const int c = wc * 64 + ct * 16 + lm;
            bfh[ct] = *(const bf16x8*)&Tth[c * 136 + k0 + lk * 8];
            bfl[ct] = *(const bf16x8*)&Ttl[c * 136 + k0 + lk * 8];
        }
        #pragma unroll
        for (int rt = 0; rt < 4; ++rt)
            #pragma unroll
            for (int ct = 0; ct < 4; ++ct) {
                acc2[rt][ct] = __builtin_amdgcn_mfma_f32_16x16x32_bf16(
                    afh[rt], bfh[ct], acc2[rt][ct], 0, 0, 0);
                acc2[rt][ct] = __builtin_amdgcn_mfma_f32_16x16x32_bf16(
                    afh[rt], bfl[ct], acc2[rt][ct], 0, 0, 0);
                acc2[rt][ct] = __builtin_amdgcn_mfma_f32_16x16x32_bf16(
                    afl[rt], bfh[ct], acc2[rt][ct], 0, 0, 0);
            }
    }

    // ================= epilogue + store =================
    const float csv = FINAL ? cs_sh : 0.f;
    #pragma unroll
    for (int rt = 0; rt < 4; ++rt)
        #pragma unroll
        for (int ct = 0; ct < 4; ++ct) {
            const int col  = wc * 64 + ct * 16 + lm;
            const int row0 = wr * 64 + rt * 16 + lk * 4;
            #pragma unroll
            for (int j = 0; j < 4; ++j) {
                const int row = row0 + j;
                float o = acc2[rt][ct][j];
                if (FINAL) {
                    o += Lp[base + (size_t)row * KK + col]
                       + csv * Lq[base + (size_t)row * KK + col]
                       + obs[(size_t)row * KK + col];
                }
                Out[base + (size_t)row * KK + col] = o;
            }
        }
}

// ---------------------------------------------------------------------------
// Split-transpose: S (f32, [1024][16384]) -> Sth/Stl (bf16, [16384][1024]).
// ---------------------------------------------------------------------------
__global__ __launch_bounds__(256) void split_transpose_kernel(
    const float* __restrict__ S,
    unsigned short* __restrict__ Th, unsigned short* __restrict__ Tl)
{
    __shared__ float tile[128][132];
    const int tid = threadIdx.x;
    const int c0  = blockIdx.x * 128;
    const int k0  = blockIdx.y * 128;

    #pragma unroll
    for (int it = 0; it < 16; ++it) {
        int gid = it * 256 + tid;
        int kk  = gid >> 5;
        int c4  = (gid & 31) * 4;
        float4 v = *(const float4*)(S + (size_t)(k0 + kk) * 16384 + c0 + c4);
        *(float4*)&tile[kk][c4] = v;
    }
    __syncthreads();
    #pragma unroll
    for (int it = 0; it < 8; ++it) {
        int gid = it * 256 + tid;
        int c   = gid >> 4;
        int kc  = (gid & 15) * 8;
        u16x8 h, l;
        #pragma unroll
        for (int j = 0; j < 8; ++j) {
            float x = tile[kc + j][c];
            unsigned int hb = bf16rne(x);
            float hf = __uint_as_float(hb << 16);
            h[j] = (unsigned short)hb;
            l[j] = (unsigned short)bf16rne(x - hf);
        }
        size_t o = (size_t)(c0 + c) * 1024 + k0 + kc;
        *(u16x8*)(Th + o) = h;
        *(u16x8*)(Tl + o) = l;
    }
}

// ---------------------------------------------------------------------------
// beta pre-split: beta f32 [i][k] -> hi/lo bf16 [i][k], diagonal zeroed.
// Same bf16rne sequence as the old in-GEMM split => bit-identical results.
// ---------------------------------------------------------------------------
__global__ __launch_bounds__(256) void beta_split_kernel(
    const float* __restrict__ beta,
    unsigned short* __restrict__ Bh, unsigned short* __restrict__ Bl)
{
    const int gid = blockIdx.x * 256 + threadIdx.x;   // 262144 threads
    const int r   = gid >> 8;
    const int c4  = (gid & 255) * 4;
    float4 v = *(const float4*)(beta + (size_t)r * NN + c4);
    if (r == c4 + 0) v.x = 0.f;
    if (r == c4 + 1) v.y = 0.f;
    if (r == c4 + 2) v.z = 0.f;
    if (r == c4 + 3) v.w = 0.f;
    float xs[4] = {v.x, v.y, v.z, v.w};
    unsigned short hs[4], ls[4];
    #pragma unroll
    for (int j = 0; j < 4; ++j) {
        unsigned int hb = bf16rne(xs[j]);
        hs[j] = (unsigned short)hb;
        ls[j] = (unsigned short)bf16rne(xs[j] - __uint_as_float(hb << 16));
    }
    *(ushort4*)(Bh + (size_t)r * NN + c4) = make_ushort4(hs[0], hs[1], hs[2], hs[3]);
    *(ushort4*)(Bl + (size_t)r * NN + c4) = make_ushort4(ls[0], ls[1], ls[2], ls[3]);
}

// ---------------------------------------------------------------------------
// Big GEMM via MFMA, split-bf16 (3 products: hh + hl + lh):
//   W[i][c] = sum_k beta_nd[i][k] * S[k][c]   (M=1024, N=16384, K=1024)
// PRESPLIT: A loads pre-split beta hi/lo directly (no per-iter VALU split —
// the old path re-split each beta panel 128x redundantly and was VALU-bound).
// LDS stride 44 shorts (22 dwords, gcd(22,32)=2): fragment reads hit 16
// distinct banks (was stride 40 = 2-way + staging conflicts).
// ---------------------------------------------------------------------------
template<bool PRESPLIT>
__global__ __launch_bounds__(256) void gemm_beta_mfma(
    const float* __restrict__ beta,
    const unsigned short* __restrict__ Bth_g,
    const unsigned short* __restrict__ Btl_g,
    const unsigned short* __restrict__ Sth,
    const unsigned short* __restrict__ Stl,
    float* __restrict__ W)
{
    __shared__ unsigned short Ah[128][44], Al[128][44];
    __shared__ unsigned short Bh[128][44], Bl[128][44];

    const int tid  = threadIdx.x;
    const int lane = tid & 63;
    const int wid  = tid >> 6;
    const int wr   = wid >> 1, wc = wid & 1;
    const int lm   = lane & 15;
    const int lk   = lane >> 4;
    const int i0   = blockIdx.y * 128;
    const int cb   = blockIdx.x * 128;

    f32x4 acc[4][4];
    #pragma unroll
    for (int a = 0; a < 4; ++a)
        #pragma unroll
        for (int b = 0; b < 4; ++b) acc[a][b] = (f32x4){0.f, 0.f, 0.f, 0.f};

    for (int k0 = 0; k0 < 1024; k0 += 32) {
        if (PRESPLIT) {
            #pragma unroll
            for (int it = 0; it < 2; ++it) {
                int gid = it * 256 + tid;
                int r   = gid >> 2;
                int kc  = (gid & 3) * 8;
                size_t o = (size_t)(i0 + r) * NN + k0 + kc;
                *(u16x8*)&Ah[r][kc] = *(const u16x8*)(Bth_g + o);
                *(u16x8*)&Al[r][kc] = *(const u16x8*)(Btl_g + o);
            }
        } else {
            #pragma unroll
            for (int it = 0; it < 4; ++it) {
                int gid = it * 256 + tid;
                int r   = gid >> 3;
                int c4  = (gid & 7) * 4;
                int gi  = i0 + r;
                float4 v = *(const float4*)(beta + (size_t)gi * NN + k0 + c4);
                if (gi == k0 + c4 + 0) v.x = 0.f;
                if (gi == k0 + c4 + 1) v.y = 0.f;
                if (gi == k0 + c4 + 2) v.z = 0.f;
                if (gi == k0 + c4 + 3) v.w = 0.f;
                float xs[4] = {v.x, v.y, v.z, v.w};
                unsigned short hs[4], ls[4];
                #pragma unroll
                for (int j = 0; j < 4; ++j) {
                    unsigned int hb = bf16rne(xs[j]);
                    hs[j] = (unsigned short)hb;
                    ls[j] = (unsigned short)bf16rne(xs[j] - __uint_as_float(hb << 16));
                }
                *(ushort4*)&Ah[r][c4] = make_ushort4(hs[0], hs[1], hs[2], hs[3]);
                *(ushort4*)&Al[r][c4] = make_ushort4(ls[0], ls[1], ls[2], ls[3]);
            }
        }
        #pragma unroll
        for (int it = 0; it < 2; ++it) {
            int gid = it * 256 + tid;
            int c   = gid >> 2;
            int kc  = (gid & 3) * 8;
            size_t o = (size_t)(cb + c) * 1024 + k0 + kc;
            *(u16x8*)&Bh[c][kc] = *(const u16x8*)(Sth + o);
            *(u16x8*)&Bl[c][kc] = *(const u16x8*)(Stl + o);
        }
        __syncthreads();

        bf16x8 afh[4], afl[4], bfh[4], bfl[4];
        #pragma unroll
        for (int rt = 0; rt < 4; ++rt) {
            const int r = wr * 64 + rt * 16 + lm;
            afh[rt] = *(const bf16x8*)&Ah[r][lk * 8];
            afl[rt] = *(const bf16x8*)&Al[r][lk * 8];
        }
        #pragma unroll
        for (int ct = 0; ct < 4; ++ct) {
            const int c = wc * 64 + ct * 16 + lm;
            bfh[ct] = *(const bf16x8*)&Bh[c][lk * 8];
            bfl[ct] = *(const bf16x8*)&Bl[c][lk * 8];
        }
        #pragma unroll
        for (int rt = 0; rt < 4; ++rt)
            #pragma unroll
            for (int ct = 0; ct < 4; ++ct) {
                acc[rt][ct] = __builtin_amdgcn_mfma_f32_16x16x32_bf16(
                    afh[rt], bfh[ct], acc[rt][ct], 0, 0, 0);
                acc[rt][ct] = __builtin_amdgcn_mfma_f32_16x16x32_bf16(
                    afh[rt], bfl[ct], acc[rt][ct], 0, 0, 0);
                acc[rt][ct] = __builtin_amdgcn_mfma_f32_16x16x32_bf16(
                    afl[rt], bfh[ct], acc[rt][ct], 0, 0, 0);
            }
        __syncthreads();
    }

    #pragma unroll
    for (int rt = 0; rt < 4; ++rt)
        #pragma unroll
        for (int ct = 0; ct < 4; ++ct) {
            const int col = cb + wc * 64 + ct * 16 + lm;
            #pragma unroll
            for (int j = 0; j < 4; ++j) {
                const int row = i0 + wr * 64 + rt * 16 + lk * 4 + j;
                W[(size_t)row * 16384 + col] = acc[rt][ct][j];
            }
        }
}

// ---------------------------------------------------------------------------
// Batched 128x128 inverse — BLOCKED Gauss-Jordan, NB=4, NO pivoting.
// (unchanged from round 8 — 8x8 tile/thread mapping)
// ---------------------------------------------------------------------------
__global__ __launch_bounds__(256) void invert_kernel(
    const float* __restrict__ Om, float* __restrict__ Inv)
{
    const int n   = blockIdx.x;
    const int tid = threadIdx.x;
    const int rg  = tid >> 4;
    const int cg  = tid & 15;
    const int r0  = rg * 8;
    const int c0  = cg * 8;
    const size_t base = (size_t)n * (KK * KK);

    float4 a4[8][2];
    #pragma unroll
    for (int i = 0; i < 8; ++i) {
        const float* src = Om + base + (size_t)(r0 + i) * KK + c0;
        a4[i][0] = *(const float4*)(src);
        a4[i][1] = *(const float4*)(src + 4);
    }

    __shared__ __align__(16) float rowblk[2][4][132];
    __shared__ __align__(16) float rowstar[2][4][132];
    __shared__ __align__(16) float cpan[2][128][4];

    for (int g = 0; g < 32; ++g) {
        const int buf = g & 1;
        const int pg  = g >> 1;
        const int sub = g & 1;

        if (rg == pg) {
            if (sub == 0) {
                #pragma unroll
                for (int p = 0; p < 4; ++p) {
                    *(float4*)&rowblk[buf][p][c0]     = a4[p][0];
                    *(float4*)&rowblk[buf][p][c0 + 4] = a4[p][1];
                }
            } else {
                #pragma unroll
                for (int p = 0; p < 4; ++p) {
                    *(float4*)&rowblk[buf][p][c0]     = a4[4 + p][0];
                    *(float4*)&rowblk[buf][p][c0 + 4] = a4[4 + p][1];
                }
            }
        }
        if (cg == pg) {
            if (sub == 0) {
                #pragma unroll
                for (int i = 0; i < 8; ++i)
                    *(float4*)&cpan[buf][r0 + i][0] = a4[i][0];
            } else {
                #pragma unroll
                for (int i = 0; i < 8; ++i)
                    *(float4*)&cpan[buf][r0 + i][0] = a4[i][1];
            }
        }
        __syncthreads();

        float4 p0 = *(const float4*)&rowblk[buf][0][4 * g];
        float4 p1 = *(const float4*)&rowblk[buf][1][4 * g];
        float4 p2 = *(const float4*)&rowblk[buf][2][4 * g];
        float4 p3 = *(const float4*)&rowblk[buf][3][4 * g];
        const float s0 = p0.x*p1.y - p1.x*p0.y;
        const float s1 = p0.x*p1.z - p1.x*p0.z;
        const float s2 = p0.x*p1.w - p1.x*p0.w;
        const float s3 = p0.y*p1.z - p1.y*p0.z;
        const float s4 = p0.y*p1.w - p1.y*p0.w;
        const float s5 = p0.z*p1.w - p1.z*p0.w;
        const float c5 = p2.z*p3.w - p3.z*p2.w;
        const float c4 = p2.y*p3.w - p3.y*p2.w;
        const float c3 = p2.y*p3.z - p3.y*p2.z;
        const float c2 = p2.x*p3.w - p3.x*p2.w;
        const float c1 = p2.x*p3.z - p3.x*p2.z;
        const float c0f = p2.x*p3.y - p3.x*p2.y;
        const float det = s0*c5 - s1*c4 + s2*c3 + s3*c2 - s4*c1 + s5*c0f;
        const float id  = 1.0f / det;
        const float Pi00 = ( p1.y*c5 - p1.z*c4 + p1.w*c3) * id;
        const float Pi01 = (-p0.y*c5 + p0.z*c4 - p0.w*c3) * id;
        const float Pi02 = ( p3.y*s5 - p3.z*s4 + p3.w*s3) * id;
        const float Pi03 = (-p2.y*s5 + p2.z*s4 - p2.w*s3) * id;
        const float Pi10 = (-p1.x*c5 + p1.z*c2 - p1.w*c1) * id;
        const float Pi11 = ( p0.x*c5 - p0.z*c2 + p0.w*c1) * id;
        const float Pi12 = (-p3.x*s5 + p3.z*s2 - p3.w*s1) * id;
        const float Pi13 = ( p2.x*s5 - p2.z*s2 + p2.w*s1) * id;
        const float Pi20 = ( p1.x*c4 - p1.y*c2 + p1.w*c0f) * id;
        const float Pi21 = (-p0.x*c4 + p0.y*c2 - p0.w*c0f) * id;
        const float Pi22 = ( p3.x*s4 - p3.y*s2 + p3.w*s0) * id;
        const float Pi23 = (-p2.x*s4 + p2.y*s2 - p2.w*s0) * id;
        const float Pi30 = (-p1.x*c3 + p1.y*c1 - p1.z*c0f) * id;
        const float Pi31 = ( p0.x*c3 - p0.y*c1 + p0.z*c0f) * id;
        const float Pi32 = (-p3.x*s3 + p3.y*s1 - p3.z*s0) * id;
        const float Pi33 = ( p2.x*s3 - p2.y*s1 + p2.z*s0) * id;

        {
            const int c = tid & 127;
            const float r0v = rowblk[buf][0][c];
            const float r1v = rowblk[buf][1][c];
            const float r2v = rowblk[buf][2][c];
            const float r3v = rowblk[buf][3][c];
            const int cl = c - 4 * g;
            if (tid < 128) {
                float v0 = Pi00*r0v + Pi01*r1v + Pi02*r2v + Pi03*r3v;
                float v1 = Pi10*r0v + Pi11*r1v + Pi12*r2v + Pi13*r3v;
                if      (cl == 0) { v0 += Pi00; v1 += Pi10; }
                else if (cl == 1) { v0 += Pi01; v1 += Pi11; }
                else if (cl == 2) { v0 += Pi02; v1 += Pi12; }
                else if (cl == 3) { v0 += Pi03; v1 += Pi13; }
                rowstar[buf][0][c] = v0;
                rowstar[buf][1][c] = v1;
            } else {
                float v2 = Pi20*r0v + Pi21*r1v + Pi22*r2v + Pi23*r3v;
                float v3 = Pi30*r0v + Pi31*r1v + Pi32*r2v + Pi33*r3v;
                if      (cl == 0) { v2 += Pi20; v3 += Pi30; }
                else if (cl == 1) { v2 += Pi21; v3 += Pi31; }
                else if (cl == 2) { v2 += Pi22; v3 += Pi32; }
                else if (cl == 3) { v2 += Pi23; v3 += Pi33; }
                rowstar[buf][2][c] = v2;
                rowstar[buf][3][c] = v3;
            }
        }
        __syncthreads();

        float4 rs0a = *(const float4*)&rowstar[buf][0][c0];
        float4 rs0b = *(const float4*)&rowstar[buf][0][c0 + 4];
        float4 rs1a = *(const float4*)&rowstar[buf][1][c0];
        float4 rs1b = *(const float4*)&rowstar[buf][1][c0 + 4];
        float4 rs2a = *(const float4*)&rowstar[buf][2][c0];
        float4 rs2b = *(const float4*)&rowstar[buf][2][c0 + 4];
        float4 rs3a = *(const float4*)&rowstar[buf][3][c0];
        float4 rs3b = *(const float4*)&rowstar[buf][3][c0 + 4];

        const bool piv_rg = (rg == pg);
        #pragma unroll
        for (int i = 0; i < 8; ++i) {
            float4 f = *(const float4*)&cpan[buf][r0 + i][0];
            if (piv_rg) {
                if (sub == 0) {
                    if (i == 0) f.x -= 1.0f;
                    if (i == 1) f.y -= 1.0f;
                    if (i == 2) f.z -= 1.0f;
                    if (i == 3) f.w -= 1.0f;
                } else {
                    if (i == 4) f.x -= 1.0f;
                    if (i == 5) f.y -= 1.0f;
                    if (i == 6) f.z -= 1.0f;
                    if (i == 7) f.w -= 1.0f;
                }
            }
            a4[i][0].x = fmaf(-f.x, rs0a.x, fmaf(-f.y, rs1a.x, fmaf(-f.z, rs2a.x, fmaf(-f.w, rs3a.x, a4[i][0].x))));
            a4[i][0].y = fmaf(-f.x, rs0a.y, fmaf(-f.y, rs1a.y, fmaf(-f.z, rs2a.y, fmaf(-f.w, rs3a.y, a4[i][0].y))));
            a4[i][0].z = fmaf(-f.x, rs0a.z, fmaf(-f.y, rs1a.z, fmaf(-f.z, rs2a.z, fmaf(-f.w, rs3a.z, a4[i][0].z))));
            a4[i][0].w = fmaf(-f.x, rs0a.w, fmaf(-f.y, rs1a.w, fmaf(-f.z, rs2a.w, fmaf(-f.w, rs3a.w, a4[i][0].w))));
            a4[i][1].x = fmaf(-f.x, rs0b.x, fmaf(-f.y, rs1b.x, fmaf(-f.z, rs2b.x, fmaf(-f.w, rs3b.x, a4[i][1].x))));
            a4[i][1].y = fmaf(-f.x, rs0b.y, fmaf(-f.y, rs1b.y, fmaf(-f.z, rs2b.y, fmaf(-f.w, rs3b.y, a4[i][1].y))));
            a4[i][1].z = fmaf(-f.x, rs0b.z, fmaf(-f.y, rs1b.z, fmaf(-f.z, rs2b.z, fmaf(-f.w, rs3b.z, a4[i][1].z))));
            a4[i][1].w = fmaf(-f.x, rs0b.w, fmaf(-f.y, rs1b.w, fmaf(-f.z, rs2b.w, fmaf(-f.w, rs3b.w, a4[i][1].w))));
        }
    }

    #pragma unroll
    for (int i = 0; i < 8; ++i) {
        float* dst = Inv + base + (size_t)(r0 + i) * KK + c0;
        *(float4*)(dst)     = a4[i][0];
        *(float4*)(dst + 4) = a4[i][1];
    }
}

// ---------------------------------------------------------------------------
extern "C" void kernel_launch(void* const* d_in, const int* in_sizes, int n_in,
                              void* d_out, int out_size, void* d_ws, size_t ws_size,
                              hipStream_t stream)
{
    const float* beta  = (const float*)d_in[0];
    const float* omega = (const float*)d_in[1];
    const float* Lp    = (const float*)d_in[2];
    const float* Lq    = (const float*)d_in[3];
    const float* obs   = (const float*)d_in[4];
    float* out = (float*)d_out;

    const size_t MATE = (size_t)NN * KK * KK;      // 16.8M elements (64 MB f32)

    if (ws_size >= 2 * MATE * sizeof(float)) {
        // big path:
        //   [S f32 64MB           ][Sth bf16 32MB][Stl bf16 32MB]
        // after transpose, S region is dead; reuse:
        //   [Bh 2MB][Bl 2MB][Inv 64MB ----(tail overlaps Sth, dead post-gemm)]
        float* S = (float*)d_ws;
        unsigned short* Sth = (unsigned short*)((char*)d_ws + MATE * sizeof(float));
        unsigned short* Stl = Sth + MATE;
        unsigned short* Bh  = (unsigned short*)d_ws;
        unsigned short* Bl  = Bh + (size_t)NN * NN;
        float* Inv  = (float*)((char*)d_ws + 2 * (size_t)NN * NN * sizeof(unsigned short));
        float* Wbuf = out;

        sandwich_mfma<false><<<dim3(NN), dim3(256), 0, stream>>>(
            Lq, omega, S, nullptr, nullptr, nullptr, nullptr);
        split_transpose_kernel<<<dim3(128, 8), dim3(256), 0, stream>>>(S, Sth, Stl);
        beta_split_kernel<<<dim3(1024), dim3(256), 0, stream>>>(beta, Bh, Bl);
        gemm_beta_mfma<true><<<dim3(128, 8), dim3(256), 0, stream>>>(
            beta, Bh, Bl, Sth, Stl, Wbuf);
        invert_kernel<<<dim3(NN), dim3(256), 0, stream>>>(omega, Inv);
        sandwich_mfma<true><<<dim3(NN), dim3(256), 0, stream>>>(
            Wbuf, Inv, out, Lp, Lq, obs, beta);
    } else {
        // tight path (unchanged): Sth/Stl borrow d_out; on-the-fly beta split
        float* S = (float*)d_ws;
        unsigned short* Sth = (unsigned short*)out;
        unsigned short* Stl = Sth + MATE;
        float* Wbuf = (float*)d_ws;
        float* Inv  = out;

        sandwich_mfma<false><<<dim3(NN), dim3(256), 0, stream>>>(
            Lq, omega, S, nullptr, nullptr, nullptr, nullptr);
        split_transpose_kernel<<<dim3(128, 8), dim3(256), 0, stream>>>(S, Sth, Stl);
        gemm_beta_mfma<false><<<dim3(128, 8), dim3(256), 0, stream>>>(
            beta, nullptr, nullptr, Sth, Stl, Wbuf);
        invert_kernel<<<dim3(NN), dim3(256), 0, stream>>>(omega, Inv);
        sandwich_mfma<true><<<dim3(NN), dim3(256), 0, stream>>>(
            Wbuf, Inv, out, Lp, Lq, obs, beta);
    }
}

// Round 10
// 409.717 us; speedup vs baseline: 1.2646x; 1.0536x over previous
//
#include <hip/hip_runtime.h>

#define NN 1024
#define KK 128

typedef __attribute__((ext_vector_type(8))) short bf16x8;
typedef __attribute__((ext_vector_type(4))) float f32x4;
typedef __attribute__((ext_vector_type(8))) unsigned short u16x8;

__device__ __forceinline__ unsigned int bf16rne(float x) {
    unsigned int u = __float_as_uint(x);
    return (u + 0x7FFFu + ((u >> 16) & 1u)) >> 16;
}

__device__ __forceinline__ void split8(const float* xs, bf16x8& h8, bf16x8& l8) {
    #pragma unroll
    for (int j = 0; j < 8; ++j) {
        unsigned int hb = bf16rne(xs[j]);
        float hf = __uint_as_float(hb << 16);
        h8[j] = (short)hb;
        l8[j] = (short)bf16rne(xs[j] - hf);
    }
}

// ---------------------------------------------------------------------------
// MFMA sandwich: Out_n = B_n^T (A_n B_n)  [+ epilogue for FINAL], split-bf16.
// 512 threads / 8 waves (wave grid 4 row-groups x 2 col-groups; wave tile
// 32x64: rt 0..1, ct 0..3). Was 256 thr / 4 waves = 1 wave/SIMD at 1
// block/CU (139KB LDS) -> pure latency-bound. 8 waves give 2 waves/SIMD
// for latency hiding; per-output FP sequence identical -> bit-identical.
// ---------------------------------------------------------------------------
template<bool FINAL>
__global__ __launch_bounds__(512) void sandwich_mfma(
    const float* __restrict__ A_, const float* __restrict__ B_,
    float* __restrict__ Out,
    const float* __restrict__ Lp, const float* __restrict__ Lq,
    const float* __restrict__ obs, const float* __restrict__ beta)
{
    __shared__ short lds_buf[69632];
    short* Bth = lds_buf;
    short* Btl = lds_buf + 17408;
    short* Tth = lds_buf + 34816;
    short* Ttl = lds_buf + 52224;
    float* pan = (float*)(lds_buf + 34816);
    __shared__ float wred[8];
    __shared__ float cs_sh;

    const int n    = blockIdx.x;
    const int tid  = threadIdx.x;
    const int lane = tid & 63;
    const int wid  = tid >> 6;          // 0..7
    const int wr   = wid >> 1;          // 0..3 row group (32 rows)
    const int wc   = wid & 1;           // 0..1 col group (64 cols)
    const int lm   = lane & 15;
    const int lk   = lane >> 4;
    const size_t base = (size_t)n * (KK * KK);

    if (FINAL) {
        float s = 0.f;
        for (int j = tid; j < NN; j += 512)
            if (j != n) s += beta[(size_t)j * NN + n];
        #pragma unroll
        for (int off = 32; off >= 1; off >>= 1) s += __shfl_down(s, off);
        if (lane == 0) wred[wid] = s;
        __syncthreads();
        if (tid == 0) {
            float t = 0.f;
            #pragma unroll
            for (int w = 0; w < 8; ++w) t += wred[w];
            cs_sh = t;
        }
    }

    // ---- stage Bt = B^T (hi/lo bf16) via two 64-col f32 panels ----
    #pragma unroll
    for (int cp = 0; cp < 2; ++cp) {
        #pragma unroll
        for (int it = 0; it < 4; ++it) {
            int gid = it * 512 + tid;       // 2048 float4 slots
            int k   = gid >> 4;
            int c4  = (gid & 15) * 4;
            *(float4*)&pan[k * 66 + c4] =
                *(const float4*)(B_ + base + (size_t)k * KK + cp * 64 + c4);
        }
        __syncthreads();
        #pragma unroll
        for (int it = 0; it < 2; ++it) {
            int t  = it * 512 + tid;        // 1024 tasks
            int c  = t >> 4;
            int ko = (t & 15) * 8;
            float xs[8];
            #pragma unroll
            for (int j = 0; j < 8; ++j) xs[j] = pan[(ko + j) * 66 + c];
            bf16x8 h8, l8;
            split8(xs, h8, l8);
            const int gc = cp * 64 + c;
            *(bf16x8*)&Bth[gc * 136 + ko] = h8;
            *(bf16x8*)&Btl[gc * 136 + ko] = l8;
        }
        __syncthreads();
    }

    // ================= stage 1: T = A @ B =================
    f32x4 acc[2][4];
    #pragma unroll
    for (int a = 0; a < 2; ++a)
        #pragma unroll
        for (int b = 0; b < 4; ++b) acc[a][b] = (f32x4){0.f, 0.f, 0.f, 0.f};

    #pragma unroll 1
    for (int ks = 0; ks < 4; ++ks) {
        const int k0 = ks * 32;
        bf16x8 afh[2], afl[2], bfh[4], bfl[4];
        #pragma unroll
        for (int rt = 0; rt < 2; ++rt) {
            const int r = wr * 32 + rt * 16 + lm;
            const float* ap = A_ + base + (size_t)r * KK + k0 + lk * 8;
            float4 x0 = *(const float4*)ap;
            float4 x1 = *(const float4*)(ap + 4);
            float xs[8] = {x0.x, x0.y, x0.z, x0.w, x1.x, x1.y, x1.z, x1.w};
            split8(xs, afh[rt], afl[rt]);
        }
        #pragma unroll
        for (int ct = 0; ct < 4; ++ct) {
            const int c = wc * 64 + ct * 16 + lm;
            bfh[ct] = *(const bf16x8*)&Bth[c * 136 + k0 + lk * 8];
            bfl[ct] = *(const bf16x8*)&Btl[c * 136 + k0 + lk * 8];
        }
        #pragma unroll
        for (int rt = 0; rt < 2; ++rt)
            #pragma unroll
            for (int ct = 0; ct < 4; ++ct) {
                acc[rt][ct] = __builtin_amdgcn_mfma_f32_16x16x32_bf16(
                    afh[rt], bfh[ct], acc[rt][ct], 0, 0, 0);
                acc[rt][ct] = __builtin_amdgcn_mfma_f32_16x16x32_bf16(
                    afh[rt], bfl[ct], acc[rt][ct], 0, 0, 0);
                acc[rt][ct] = __builtin_amdgcn_mfma_f32_16x16x32_bf16(
                    afl[rt], bfh[ct], acc[rt][ct], 0, 0, 0);
            }
    }

    // ---- T -> Tt[c][k] hi/lo (lane's 4 rows k-contiguous: 8B writes) ----
    #pragma unroll
    for (int rt = 0; rt < 2; ++rt)
        #pragma unroll
        for (int ct = 0; ct < 4; ++ct) {
            const int col  = wc * 64 + ct * 16 + lm;
            const int row0 = wr * 32 + rt * 16 + lk * 4;
            unsigned short h[4], l[4];
            #pragma unroll
            for (int j = 0; j < 4; ++j) {
                float x = acc[rt][ct][j];
                unsigned int hb = bf16rne(x);
                h[j] = (unsigned short)hb;
                l[j] = (unsigned short)bf16rne(x - __uint_as_float(hb << 16));
            }
            *(ushort4*)&Tth[col * 136 + row0] = make_ushort4(h[0], h[1], h[2], h[3]);
            *(ushort4*)&Ttl[col * 136 + row0] = make_ushort4(l[0], l[1], l[2], l[3]);
        }
    __syncthreads();

    // ================= stage 2: Out = B^T @ T =================
    f32x4 acc2[2][4];
    #pragma unroll
    for (int a = 0; a < 2; ++a)
        #pragma unroll
        for (int b = 0; b < 4; ++b) acc2[a][b] = (f32x4){0.f, 0.f, 0.f, 0.f};

    #pragma unroll 1
    for (int ks = 0; ks < 4; ++ks) {
        const int k0 = ks * 32;
        bf16x8 afh[2], afl[2], bfh[4], bfl[4];
        #pragma unroll
        for (int rt = 0; rt < 2; ++rt) {
            const int r = wr * 32 + rt * 16 + lm;
            afh[rt] = *(const bf16x8*)&Bth[r * 136 + k0 + lk * 8];
            afl[rt] = *(const bf16x8*)&Btl[r * 136 + k0 + lk * 8];
        }
        #pragma unroll
        for (int ct = 0; ct < 4; ++ct) {
            const int c = wc * 64 + ct * 16 + lm;
            bfh[ct] = *(const bf16x8*)&Tth[c * 136 + k0 + lk * 8];
            bfl[ct] = *(const bf16x8*)&Ttl[c * 136 + k0 + lk * 8];
        }
        #pragma unroll
        for (int rt = 0; rt < 2; ++rt)
            #pragma unroll
            for (int ct = 0; ct < 4; ++ct) {
                acc2[rt][ct] = __builtin_amdgcn_mfma_f32_16x16x32_bf16(
                    afh[rt], bfh[ct], acc2[rt][ct], 0, 0, 0);
                acc2[rt][ct] = __builtin_amdgcn_mfma_f32_16x16x32_bf16(
                    afh[rt], bfl[ct], acc2[rt][ct], 0, 0, 0);
                acc2[rt][ct] = __builtin_amdgcn_mfma_f32_16x16x32_bf16(
                    afl[rt], bfh[ct], acc2[rt][ct], 0, 0, 0);
            }
    }

    // ================= epilogue + store =================
    const float csv = FINAL ? cs_sh : 0.f;
    #pragma unroll
    for (int rt = 0; rt < 2; ++rt)
        #pragma unroll
        for (int ct = 0; ct < 4; ++ct) {
            const int col  = wc * 64 + ct * 16 + lm;
            const int row0 = wr * 32 + rt * 16 + lk * 4;
            #pragma unroll
            for (int j = 0; j < 4; ++j) {
                const int row = row0 + j;
                float o = acc2[rt][ct][j];
                if (FINAL) {
                    o += Lp[base + (size_t)row * KK + col]
                       + csv * Lq[base + (size_t)row * KK + col]
                       + obs[(size_t)row * KK + col];
                }
                Out[base + (size_t)row * KK + col] = o;
            }
        }
}

// ---------------------------------------------------------------------------
// Split-transpose: S (f32, [1024][16384]) -> Sth/Stl (bf16, [16384][1024]).
// ---------------------------------------------------------------------------
__global__ __launch_bounds__(256) void split_transpose_kernel(
    const float* __restrict__ S,
    unsigned short* __restrict__ Th, unsigned short* __restrict__ Tl)
{
    __shared__ float tile[128][132];
    const int tid = threadIdx.x;
    const int c0  = blockIdx.x * 128;
    const int k0  = blockIdx.y * 128;

    #pragma unroll
    for (int it = 0; it < 16; ++it) {
        int gid = it * 256 + tid;
        int kk  = gid >> 5;
        int c4  = (gid & 31) * 4;
        float4 v = *(const float4*)(S + (size_t)(k0 + kk) * 16384 + c0 + c4);
        *(float4*)&tile[kk][c4] = v;
    }
    __syncthreads();
    #pragma unroll
    for (int it = 0; it < 8; ++it) {
        int gid = it * 256 + tid;
        int c   = gid >> 4;
        int kc  = (gid & 15) * 8;
        u16x8 h, l;
        #pragma unroll
        for (int j = 0; j < 8; ++j) {
            float x = tile[kc + j][c];
            unsigned int hb = bf16rne(x);
            float hf = __uint_as_float(hb << 16);
            h[j] = (unsigned short)hb;
            l[j] = (unsigned short)bf16rne(x - hf);
        }
        size_t o = (size_t)(c0 + c) * 1024 + k0 + kc;
        *(u16x8*)(Th + o) = h;
        *(u16x8*)(Tl + o) = l;
    }
}

// ---------------------------------------------------------------------------
// beta pre-split: beta f32 [i][k] -> hi/lo bf16 [i][k], diagonal zeroed.
// ---------------------------------------------------------------------------
__global__ __launch_bounds__(256) void beta_split_kernel(
    const float* __restrict__ beta,
    unsigned short* __restrict__ Bh, unsigned short* __restrict__ Bl)
{
    const int gid = blockIdx.x * 256 + threadIdx.x;
    const int r   = gid >> 8;
    const int c4  = (gid & 255) * 4;
    float4 v = *(const float4*)(beta + (size_t)r * NN + c4);
    if (r == c4 + 0) v.x = 0.f;
    if (r == c4 + 1) v.y = 0.f;
    if (r == c4 + 2) v.z = 0.f;
    if (r == c4 + 3) v.w = 0.f;
    float xs[4] = {v.x, v.y, v.z, v.w};
    unsigned short hs[4], ls[4];
    #pragma unroll
    for (int j = 0; j < 4; ++j) {
        unsigned int hb = bf16rne(xs[j]);
        hs[j] = (unsigned short)hb;
        ls[j] = (unsigned short)bf16rne(xs[j] - __uint_as_float(hb << 16));
    }
    *(ushort4*)(Bh + (size_t)r * NN + c4) = make_ushort4(hs[0], hs[1], hs[2], hs[3]);
    *(ushort4*)(Bl + (size_t)r * NN + c4) = make_ushort4(ls[0], ls[1], ls[2], ls[3]);
}

// ---------------------------------------------------------------------------
// Big GEMM via MFMA, split-bf16 (unchanged from round 9).
// ---------------------------------------------------------------------------
template<bool PRESPLIT>
__global__ __launch_bounds__(256) void gemm_beta_mfma(
    const float* __restrict__ beta,
    const unsigned short* __restrict__ Bth_g,
    const unsigned short* __restrict__ Btl_g,
    const unsigned short* __restrict__ Sth,
    const unsigned short* __restrict__ Stl,
    float* __restrict__ W)
{
    __shared__ unsigned short Ah[128][44], Al[128][44];
    __shared__ unsigned short Bh[128][44], Bl[128][44];

    const int tid  = threadIdx.x;
    const int lane = tid & 63;
    const int wid  = tid >> 6;
    const int wr   = wid >> 1, wc = wid & 1;
    const int lm   = lane & 15;
    const int lk   = lane >> 4;
    const int i0   = blockIdx.y * 128;
    const int cb   = blockIdx.x * 128;

    f32x4 acc[4][4];
    #pragma unroll
    for (int a = 0; a < 4; ++a)
        #pragma unroll
        for (int b = 0; b < 4; ++b) acc[a][b] = (f32x4){0.f, 0.f, 0.f, 0.f};

    for (int k0 = 0; k0 < 1024; k0 += 32) {
        if (PRESPLIT) {
            #pragma unroll
            for (int it = 0; it < 2; ++it) {
                int gid = it * 256 + tid;
                int r   = gid >> 2;
                int kc  = (gid & 3) * 8;
                size_t o = (size_t)(i0 + r) * NN + k0 + kc;
                *(u16x8*)&Ah[r][kc] = *(const u16x8*)(Bth_g + o);
                *(u16x8*)&Al[r][kc] = *(const u16x8*)(Btl_g + o);
            }
        } else {
            #pragma unroll
            for (int it = 0; it < 4; ++it) {
                int gid = it * 256 + tid;
                int r   = gid >> 3;
                int c4  = (gid & 7) * 4;
                int gi  = i0 + r;
                float4 v = *(const float4*)(beta + (size_t)gi * NN + k0 + c4);
                if (gi == k0 + c4 + 0) v.x = 0.f;
                if (gi == k0 + c4 + 1) v.y = 0.f;
                if (gi == k0 + c4 + 2) v.z = 0.f;
                if (gi == k0 + c4 + 3) v.w = 0.f;
                float xs[4] = {v.x, v.y, v.z, v.w};
                unsigned short hs[4], ls[4];
                #pragma unroll
                for (int j = 0; j < 4; ++j) {
                    unsigned int hb = bf16rne(xs[j]);
                    hs[j] = (unsigned short)hb;
                    ls[j] = (unsigned short)bf16rne(xs[j] - __uint_as_float(hb << 16));
                }
                *(ushort4*)&Ah[r][c4] = make_ushort4(hs[0], hs[1], hs[2], hs[3]);
                *(ushort4*)&Al[r][c4] = make_ushort4(ls[0], ls[1], ls[2], ls[3]);
            }
        }
        #pragma unroll
        for (int it = 0; it < 2; ++it) {
            int gid = it * 256 + tid;
            int c   = gid >> 2;
            int kc  = (gid & 3) * 8;
            size_t o = (size_t)(cb + c) * 1024 + k0 + kc;
            *(u16x8*)&Bh[c][kc] = *(const u16x8*)(Sth + o);
            *(u16x8*)&Bl[c][kc] = *(const u16x8*)(Stl + o);
        }
        __syncthreads();

        bf16x8 afh[4], afl[4], bfh[4], bfl[4];
        #pragma unroll
        for (int rt = 0; rt < 4; ++rt) {
            const int r = wr * 64 + rt * 16 + lm;
            afh[rt] = *(const bf16x8*)&Ah[r][lk * 8];
            afl[rt] = *(const bf16x8*)&Al[r][lk * 8];
        }
        #pragma unroll
        for (int ct = 0; ct < 4; ++ct) {
            const int c = wc * 64 + ct * 16 + lm;
            bfh[ct] = *(const bf16x8*)&Bh[c][lk * 8];
            bfl[ct] = *(const bf16x8*)&Bl[c][lk * 8];
        }
        #pragma unroll
        for (int rt = 0; rt < 4; ++rt)
            #pragma unroll
            for (int ct = 0; ct < 4; ++ct) {
                acc[rt][ct] = __builtin_amdgcn_mfma_f32_16x16x32_bf16(
                    afh[rt], bfh[ct], acc[rt][ct], 0, 0, 0);
                acc[rt][ct] = __builtin_amdgcn_mfma_f32_16x16x32_bf16(
                    afh[rt], bfl[ct], acc[rt][ct], 0, 0, 0);
                acc[rt][ct] = __builtin_amdgcn_mfma_f32_16x16x32_bf16(
                    afl[rt], bfh[ct], acc[rt][ct], 0, 0, 0);
            }
        __syncthreads();
    }

    #pragma unroll
    for (int rt = 0; rt < 4; ++rt)
        #pragma unroll
        for (int ct = 0; ct < 4; ++ct) {
            const int col = cb + wc * 64 + ct * 16 + lm;
            #pragma unroll
            for (int j = 0; j < 4; ++j) {
                const int row = i0 + wr * 64 + rt * 16 + lk * 4 + j;
                W[(size_t)row * 16384 + col] = acc[rt][ct][j];
            }
        }
}

// ---------------------------------------------------------------------------
// Batched 128x128 inverse — BLOCKED Gauss-Jordan, NB=4, NO pivoting.
// (unchanged from round 8 — 8x8 tile/thread mapping)
// ---------------------------------------------------------------------------
__global__ __launch_bounds__(256) void invert_kernel(
    const float* __restrict__ Om, float* __restrict__ Inv)
{
    const int n   = blockIdx.x;
    const int tid = threadIdx.x;
    const int rg  = tid >> 4;
    const int cg  = tid & 15;
    const int r0  = rg * 8;
    const int c0  = cg * 8;
    const size_t base = (size_t)n * (KK * KK);

    float4 a4[8][2];
    #pragma unroll
    for (int i = 0; i < 8; ++i) {
        const float* src = Om + base + (size_t)(r0 + i) * KK + c0;
        a4[i][0] = *(const float4*)(src);
        a4[i][1] = *(const float4*)(src + 4);
    }

    __shared__ __align__(16) float rowblk[2][4][132];
    __shared__ __align__(16) float rowstar[2][4][132];
    __shared__ __align__(16) float cpan[2][128][4];

    for (int g = 0; g < 32; ++g) {
        const int buf = g & 1;
        const int pg  = g >> 1;
        const int sub = g & 1;

        if (rg == pg) {
            if (sub == 0) {
                #pragma unroll
                for (int p = 0; p < 4; ++p) {
                    *(float4*)&rowblk[buf][p][c0]     = a4[p][0];
                    *(float4*)&rowblk[buf][p][c0 + 4] = a4[p][1];
                }
            } else {
                #pragma unroll
                for (int p = 0; p < 4; ++p) {
                    *(float4*)&rowblk[buf][p][c0]     = a4[4 + p][0];
                    *(float4*)&rowblk[buf][p][c0 + 4] = a4[4 + p][1];
                }
            }
        }
        if (cg == pg) {
            if (sub == 0) {
                #pragma unroll
                for (int i = 0; i < 8; ++i)
                    *(float4*)&cpan[buf][r0 + i][0] = a4[i][0];
            } else {
                #pragma unroll
                for (int i = 0; i < 8; ++i)
                    *(float4*)&cpan[buf][r0 + i][0] = a4[i][1];
            }
        }
        __syncthreads();

        float4 p0 = *(const float4*)&rowblk[buf][0][4 * g];
        float4 p1 = *(const float4*)&rowblk[buf][1][4 * g];
        float4 p2 = *(const float4*)&rowblk[buf][2][4 * g];
        float4 p3 = *(const float4*)&rowblk[buf][3][4 * g];
        const float s0 = p0.x*p1.y - p1.x*p0.y;
        const float s1 = p0.x*p1.z - p1.x*p0.z;
        const float s2 = p0.x*p1.w - p1.x*p0.w;
        const float s3 = p0.y*p1.z - p1.y*p0.z;
        const float s4 = p0.y*p1.w - p1.y*p0.w;
        const float s5 = p0.z*p1.w - p1.z*p0.w;
        const float c5 = p2.z*p3.w - p3.z*p2.w;
        const float c4 = p2.y*p3.w - p3.y*p2.w;
        const float c3 = p2.y*p3.z - p3.y*p2.z;
        const float c2 = p2.x*p3.w - p3.x*p2.w;
        const float c1 = p2.x*p3.z - p3.x*p2.z;
        const float c0f = p2.x*p3.y - p3.x*p2.y;
        const float det = s0*c5 - s1*c4 + s2*c3 + s3*c2 - s4*c1 + s5*c0f;
        const float id  = 1.0f / det;
        const float Pi00 = ( p1.y*c5 - p1.z*c4 + p1.w*c3) * id;
        const float Pi01 = (-p0.y*c5 + p0.z*c4 - p0.w*c3) * id;
        const float Pi02 = ( p3.y*s5 - p3.z*s4 + p3.w*s3) * id;
        const float Pi03 = (-p2.y*s5 + p2.z*s4 - p2.w*s3) * id;
        const float Pi10 = (-p1.x*c5 + p1.z*c2 - p1.w*c1) * id;
        const float Pi11 = ( p0.x*c5 - p0.z*c2 + p0.w*c1) * id;
        const float Pi12 = (-p3.x*s5 + p3.z*s2 - p3.w*s1) * id;
        const float Pi13 = ( p2.x*s5 - p2.z*s2 + p2.w*s1) * id;
        const float Pi20 = ( p1.x*c4 - p1.y*c2 + p1.w*c0f) * id;
        const float Pi21 = (-p0.x*c4 + p0.y*c2 - p0.w*c0f) * id;
        const float Pi22 = ( p3.x*s4 - p3.y*s2 + p3.w*s0) * id;
        const float Pi23 = (-p2.x*s4 + p2.y*s2 - p2.w*s0) * id;
        const float Pi30 = (-p1.x*c3 + p1.y*c1 - p1.z*c0f) * id;
        const float Pi31 = ( p0.x*c3 - p0.y*c1 + p0.z*c0f) * id;
        const float Pi32 = (-p3.x*s3 + p3.y*s1 - p3.z*s0) * id;
        const float Pi33 = ( p2.x*s3 - p2.y*s1 + p2.z*s0) * id;

        {
            const int c = tid & 127;
            const float r0v = rowblk[buf][0][c];
            const float r1v = rowblk[buf][1][c];
            const float r2v = rowblk[buf][2][c];
            const float r3v = rowblk[buf][3][c];
            const int cl = c - 4 * g;
            if (tid < 128) {
                float v0 = Pi00*r0v + Pi01*r1v + Pi02*r2v + Pi03*r3v;
                float v1 = Pi10*r0v + Pi11*r1v + Pi12*r2v + Pi13*r3v;
                if      (cl == 0) { v0 += Pi00; v1 += Pi10; }
                else if (cl == 1) { v0 += Pi01; v1 += Pi11; }
                else if (cl == 2) { v0 += Pi02; v1 += Pi12; }
                else if (cl == 3) { v0 += Pi03; v1 += Pi13; }
                rowstar[buf][0][c] = v0;
                rowstar[buf][1][c] = v1;
            } else {
                float v2 = Pi20*r0v + Pi21*r1v + Pi22*r2v + Pi23*r3v;
                float v3 = Pi30*r0v + Pi31*r1v + Pi32*r2v + Pi33*r3v;
                if      (cl == 0) { v2 += Pi20; v3 += Pi30; }
                else if (cl == 1) { v2 += Pi21; v3 += Pi31; }
                else if (cl == 2) { v2 += Pi22; v3 += Pi32; }
                else if (cl == 3) { v2 += Pi23; v3 += Pi33; }
                rowstar[buf][2][c] = v2;
                rowstar[buf][3][c] = v3;
            }
        }
        __syncthreads();

        float4 rs0a = *(const float4*)&rowstar[buf][0][c0];
        float4 rs0b = *(const float4*)&rowstar[buf][0][c0 + 4];
        float4 rs1a = *(const float4*)&rowstar[buf][1][c0];
        float4 rs1b = *(const float4*)&rowstar[buf][1][c0 + 4];
        float4 rs2a = *(const float4*)&rowstar[buf][2][c0];
        float4 rs2b = *(const float4*)&rowstar[buf][2][c0 + 4];
        float4 rs3a = *(const float4*)&rowstar[buf][3][c0];
        float4 rs3b = *(const float4*)&rowstar[buf][3][c0 + 4];

        const bool piv_rg = (rg == pg);
        #pragma unroll
        for (int i = 0; i < 8; ++i) {
            float4 f = *(const float4*)&cpan[buf][r0 + i][0];
            if (piv_rg) {
                if (sub == 0) {
                    if (i == 0) f.x -= 1.0f;
                    if (i == 1) f.y -= 1.0f;
                    if (i == 2) f.z -= 1.0f;
                    if (i == 3) f.w -= 1.0f;
                } else {
                    if (i == 4) f.x -= 1.0f;
                    if (i == 5) f.y -= 1.0f;
                    if (i == 6) f.z -= 1.0f;
                    if (i == 7) f.w -= 1.0f;
                }
            }
            a4[i][0].x = fmaf(-f.x, rs0a.x, fmaf(-f.y, rs1a.x, fmaf(-f.z, rs2a.x, fmaf(-f.w, rs3a.x, a4[i][0].x))));
            a4[i][0].y = fmaf(-f.x, rs0a.y, fmaf(-f.y, rs1a.y, fmaf(-f.z, rs2a.y, fmaf(-f.w, rs3a.y, a4[i][0].y))));
            a4[i][0].z = fmaf(-f.x, rs0a.z, fmaf(-f.y, rs1a.z, fmaf(-f.z, rs2a.z, fmaf(-f.w, rs3a.z, a4[i][0].z))));
            a4[i][0].w = fmaf(-f.x, rs0a.w, fmaf(-f.y, rs1a.w, fmaf(-f.z, rs2a.w, fmaf(-f.w, rs3a.w, a4[i][0].w))));
            a4[i][1].x = fmaf(-f.x, rs0b.x, fmaf(-f.y, rs1b.x, fmaf(-f.z, rs2b.x, fmaf(-f.w, rs3b.x, a4[i][1].x))));
            a4[i][1].y = fmaf(-f.x, rs0b.y, fmaf(-f.y, rs1b.y, fmaf(-f.z, rs2b.y, fmaf(-f.w, rs3b.y, a4[i][1].y))));
            a4[i][1].z = fmaf(-f.x, rs0b.z, fmaf(-f.y, rs1b.z, fmaf(-f.z, rs2b.z, fmaf(-f.w, rs3b.z, a4[i][1].z))));
            a4[i][1].w = fmaf(-f.x, rs0b.w, fmaf(-f.y, rs1b.w, fmaf(-f.z, rs2b.w, fmaf(-f.w, rs3b.w, a4[i][1].w))));
        }
    }

    #pragma unroll
    for (int i = 0; i < 8; ++i) {
        float* dst = Inv + base + (size_t)(r0 + i) * KK + c0;
        *(float4*)(dst)     = a4[i][0];
        *(float4*)(dst + 4) = a4[i][1];
    }
}

// ---------------------------------------------------------------------------
extern "C" void kernel_launch(void* const* d_in, const int* in_sizes, int n_in,
                              void* d_out, int out_size, void* d_ws, size_t ws_size,
                              hipStream_t stream)
{
    const float* beta  = (const float*)d_in[0];
    const float* omega = (const float*)d_in[1];
    const float* Lp    = (const float*)d_in[2];
    const float* Lq    = (const float*)d_in[3];
    const float* obs   = (const float*)d_in[4];
    float* out = (float*)d_out;

    const size_t MATE = (size_t)NN * KK * KK;      // 16.8M elements (64 MB f32)

    if (ws_size >= 2 * MATE * sizeof(float)) {
        float* S = (float*)d_ws;
        unsigned short* Sth = (unsigned short*)((char*)d_ws + MATE * sizeof(float));
        unsigned short* Stl = Sth + MATE;
        unsigned short* Bh  = (unsigned short*)d_ws;
        unsigned short* Bl  = Bh + (size_t)NN * NN;
        float* Inv  = (float*)((char*)d_ws + 2 * (size_t)NN * NN * sizeof(unsigned short));
        float* Wbuf = out;

        sandwich_mfma<false><<<dim3(NN), dim3(512), 0, stream>>>(
            Lq, omega, S, nullptr, nullptr, nullptr, nullptr);
        split_transpose_kernel<<<dim3(128, 8), dim3(256), 0, stream>>>(S, Sth, Stl);
        beta_split_kernel<<<dim3(1024), dim3(256), 0, stream>>>(beta, Bh, Bl);
        gemm_beta_mfma<true><<<dim3(128, 8), dim3(256), 0, stream>>>(
            beta, Bh, Bl, Sth, Stl, Wbuf);
        invert_kernel<<<dim3(NN), dim3(256), 0, stream>>>(omega, Inv);
        sandwich_mfma<true><<<dim3(NN), dim3(512), 0, stream>>>(
            Wbuf, Inv, out, Lp, Lq, obs, beta);
    } else {
        float* S = (float*)d_ws;
        unsigned short* Sth = (unsigned short*)out;
        unsigned short* Stl = Sth + MATE;
        float* Wbuf = (float*)d_ws;
        float* Inv  = out;

        sandwich_mfma<false><<<dim3(NN), dim3(512), 0, stream>>>(
            Lq, omega, S, nullptr, nullptr, nullptr, nullptr);
        split_transpose_kernel<<<dim3(128, 8), dim3(256), 0, stream>>>(S, Sth, Stl);
        gemm_beta_mfma<false><<<dim3(128, 8), dim3(256), 0, stream>>>(
            beta, nullptr, nullptr, Sth, Stl, Wbuf);
        invert_kernel<<<dim3(NN), dim3(256), 0, stream>>>(omega, Inv);
        sandwich_mfma<true><<<dim3(NN), dim3(512), 0, stream>>>(
            Wbuf, Inv, out, Lp, Lq, obs, beta);
    }
}